// Round 4
// baseline (1008.033 us; speedup 1.0000x reference)
//
#include <hip/hip_runtime.h>
#include <hip/hip_bf16.h>
#include <math.h>
#include <stdint.h>

#define F_IN  32
#define F_HID 32
#define F_OUT 16
#define NPB     128   // nodes per bucket
#define LOG_NPB 7
#define MAX_NB  1024  // supports n <= 131072

// ---- init: deg=1 (self-loop), bcount=0 ----
__global__ void k_init(int* __restrict__ deg, int* __restrict__ bcount, int n, int nb) {
    int i = blockIdx.x * 256 + threadIdx.x;
    if (i < n) deg[i] = 1;
    if (i < nb) bcount[i] = 0;
}

// ---- degree count + bucket histogram (fused, one read of dst) ----
__global__ void k_count(const int* __restrict__ ei, int ne,
                        int* __restrict__ deg, int* __restrict__ bcount, int nb) {
    __shared__ int hist[MAX_NB];
    int t = threadIdx.x;
    for (int i = t; i < nb; i += 256) hist[i] = 0;
    __syncthreads();
    for (long e = (long)blockIdx.x * 256 + t; e < ne; e += (long)gridDim.x * 256) {
        int dn = ei[ne + e];
        atomicAdd(&deg[dn], 1);
        atomicAdd(&hist[dn >> LOG_NPB], 1);
    }
    __syncthreads();
    for (int i = t; i < nb; i += 256) {
        int v = hist[i];
        if (v) atomicAdd(&bcount[i], v);
    }
}

__global__ void k_dinv(const int* __restrict__ deg, float* __restrict__ dinv, int n) {
    int i = blockIdx.x * 256 + threadIdx.x;
    if (i < n) dinv[i] = rsqrtf((float)deg[i]);
}

// ---- exclusive scan of bcount -> boff[0..nb], bcur copy (single block) ----
__global__ void k_bscan(const int* __restrict__ bcount, int* __restrict__ boff,
                        int* __restrict__ bcur, int nb) {
    __shared__ int sh[256];
    int t = threadIdx.x;
    int base = t * 4;
    int v[4], s = 0;
    #pragma unroll
    for (int j = 0; j < 4; ++j) {
        v[j] = (base + j < nb) ? bcount[base + j] : 0;
        s += v[j];
    }
    sh[t] = s; __syncthreads();
    for (int o = 1; o < 256; o <<= 1) {
        int u = (t >= o) ? sh[t - o] : 0;
        __syncthreads();
        sh[t] += u;
        __syncthreads();
    }
    int run = sh[t] - s;  // exclusive prefix of this thread's chunk
    #pragma unroll
    for (int j = 0; j < 4; ++j) {
        int idx = base + j;
        if (idx < nb) { boff[idx] = run; bcur[idx] = run; run += v[j]; }
    }
    if (t == 0) boff[nb] = sh[255];
}

// ---- bucket fill: ebuf[p] = src | (localDst<<17), 4B/edge ----
__global__ void k_bfill(const int* __restrict__ ei, int ne,
                        int* __restrict__ bcur, uint32_t* __restrict__ ebuf) {
    long e = (long)blockIdx.x * 256 + threadIdx.x;
    if (e >= ne) return;
    int sn = ei[e], dn = ei[ne + e];
    int b = dn >> LOG_NPB;
    int p = atomicAdd(&bcur[b], 1);
    ebuf[p] = (uint32_t)sn | ((uint32_t)(dn & (NPB - 1)) << 17);
}

// ---- g1 = (x @ W1) * dinv, packed f16x2 (16 words/node) ----
__launch_bounds__(256)
__global__ void k_mm1(const float* __restrict__ x, const float* __restrict__ W1,
                      const float* __restrict__ dinv, uint32_t* __restrict__ g1, int n) {
    __shared__ float Ws[F_IN * F_HID];
    __shared__ float xs[8 * F_IN];
    int t = threadIdx.x;
    for (int i = t; i < F_IN * F_HID; i += 256) Ws[i] = W1[i];
    int nl = t >> 5, c = t & 31;
    int node = blockIdx.x * 8 + nl;
    if (node < n) xs[t] = x[(size_t)node * F_IN + c];
    __syncthreads();
    if (node >= n) return;
    float sum = 0.f;
    #pragma unroll
    for (int k = 0; k < F_IN; ++k) sum += xs[nl * F_IN + k] * Ws[k * F_HID + c];
    float gv = sum * dinv[node];
    float hi = __shfl_xor(gv, 1);
    if ((c & 1) == 0) {
        union { _Float16 h[2]; uint32_t u; } pk;
        pk.h[0] = (_Float16)gv; pk.h[1] = (_Float16)hi;
        g1[(size_t)node * 16 + (c >> 1)] = pk.u;
    }
}

// ---- agg layer 1: LDS accumulate per bucket, epilogue tanh(dinv*s + b1) ----
__launch_bounds__(256)
__global__ void k_agg1(const uint32_t* __restrict__ g1, const uint32_t* __restrict__ ebuf,
                       const int* __restrict__ boff, const float* __restrict__ dinv,
                       const float* __restrict__ b1, float* __restrict__ h, int n) {
    __shared__ float acc[NPB * 33];  // padded stride 33
    int b = blockIdx.x, t = threadIdx.x;
    int v0 = b << LOG_NPB;
    // seed with self-loop term g1[v]
    for (int i = t; i < NPB * 16; i += 256) {
        int l = i >> 4, cp = i & 15;
        int v = v0 + l;
        float x0 = 0.f, x1 = 0.f;
        if (v < n) {
            union { uint32_t u; _Float16 h2[2]; } pk;
            pk.u = g1[(size_t)v * 16 + cp];
            x0 = (float)pk.h2[0]; x1 = (float)pk.h2[1];
        }
        acc[l * 33 + 2 * cp]     = x0;
        acc[l * 33 + 2 * cp + 1] = x1;
    }
    __syncthreads();
    int start = boff[b], end = boff[b + 1];
    for (int i = start + t; i < end; i += 256) {
        uint32_t u = ebuf[i];
        int sn = u & 0x1FFFF;
        int ld = u >> 17;
        const uint4* row = (const uint4*)(g1 + (size_t)sn * 16);
        float* dst = &acc[ld * 33];
        #pragma unroll
        for (int q = 0; q < 4; ++q) {
            uint4 w = row[q];
            union { uint32_t u; _Float16 h2[2]; } p0, p1, p2, p3;
            p0.u = w.x; p1.u = w.y; p2.u = w.z; p3.u = w.w;
            atomicAdd(&dst[q * 8 + 0], (float)p0.h2[0]);
            atomicAdd(&dst[q * 8 + 1], (float)p0.h2[1]);
            atomicAdd(&dst[q * 8 + 2], (float)p1.h2[0]);
            atomicAdd(&dst[q * 8 + 3], (float)p1.h2[1]);
            atomicAdd(&dst[q * 8 + 4], (float)p2.h2[0]);
            atomicAdd(&dst[q * 8 + 5], (float)p2.h2[1]);
            atomicAdd(&dst[q * 8 + 6], (float)p3.h2[0]);
            atomicAdd(&dst[q * 8 + 7], (float)p3.h2[1]);
        }
    }
    __syncthreads();
    for (int i = t; i < NPB * F_HID; i += 256) {
        int l = i >> 5, c = i & 31;
        int v = v0 + l;
        if (v < n)
            h[(size_t)v * F_HID + c] = tanhf(acc[l * 33 + c] * dinv[v] + b1[c]);
    }
}

// ---- g2 = (h @ W2) * dinv, packed f16x2 (8 words/node) ----
__launch_bounds__(256)
__global__ void k_mm2(const float* __restrict__ h, const float* __restrict__ W2,
                      const float* __restrict__ dinv, uint32_t* __restrict__ g2, int n) {
    __shared__ float Ws[F_HID * F_OUT];
    __shared__ float hs[16 * F_HID];
    int t = threadIdx.x;
    for (int i = t; i < F_HID * F_OUT; i += 256) Ws[i] = W2[i];
    int node0 = blockIdx.x * 16;
    for (int i = t; i < 16 * F_HID; i += 256) {
        int nl = i >> 5, k = i & 31;
        int node = node0 + nl;
        hs[i] = (node < n) ? h[(size_t)node * F_HID + k] : 0.f;
    }
    __syncthreads();
    int nl = t >> 4, c = t & 15;
    int node = node0 + nl;
    if (node >= n) return;
    float s = 0.f;
    #pragma unroll
    for (int k = 0; k < F_HID; ++k) s += hs[nl * F_HID + k] * Ws[k * F_OUT + c];
    float gv = s * dinv[node];
    float hi = __shfl_xor(gv, 1);
    if ((c & 1) == 0) {
        union { _Float16 h[2]; uint32_t u; } pk;
        pk.h[0] = (_Float16)gv; pk.h[1] = (_Float16)hi;
        g2[(size_t)node * 8 + (c >> 1)] = pk.u;
    }
}

// ---- agg layer 2: LDS accumulate + bias + log_softmax (fused final) ----
__launch_bounds__(256)
__global__ void k_agg2(const uint32_t* __restrict__ g2, const uint32_t* __restrict__ ebuf,
                       const int* __restrict__ boff, const float* __restrict__ dinv,
                       const float* __restrict__ b2,
                       float* __restrict__ out_h, float* __restrict__ out_ls, int n) {
    __shared__ float acc[NPB * 17];  // padded stride 17
    int b = blockIdx.x, t = threadIdx.x;
    int v0 = b << LOG_NPB;
    for (int i = t; i < NPB * 8; i += 256) {
        int l = i >> 3, cp = i & 7;
        int v = v0 + l;
        float x0 = 0.f, x1 = 0.f;
        if (v < n) {
            union { uint32_t u; _Float16 h2[2]; } pk;
            pk.u = g2[(size_t)v * 8 + cp];
            x0 = (float)pk.h2[0]; x1 = (float)pk.h2[1];
        }
        acc[l * 17 + 2 * cp]     = x0;
        acc[l * 17 + 2 * cp + 1] = x1;
    }
    __syncthreads();
    int start = boff[b], end = boff[b + 1];
    for (int i = start + t; i < end; i += 256) {
        uint32_t u = ebuf[i];
        int sn = u & 0x1FFFF;
        int ld = u >> 17;
        const uint4* row = (const uint4*)(g2 + (size_t)sn * 8);
        float* dst = &acc[ld * 17];
        #pragma unroll
        for (int q = 0; q < 2; ++q) {
            uint4 w = row[q];
            union { uint32_t u; _Float16 h2[2]; } p0, p1, p2, p3;
            p0.u = w.x; p1.u = w.y; p2.u = w.z; p3.u = w.w;
            atomicAdd(&dst[q * 8 + 0], (float)p0.h2[0]);
            atomicAdd(&dst[q * 8 + 1], (float)p0.h2[1]);
            atomicAdd(&dst[q * 8 + 2], (float)p1.h2[0]);
            atomicAdd(&dst[q * 8 + 3], (float)p1.h2[1]);
            atomicAdd(&dst[q * 8 + 4], (float)p2.h2[0]);
            atomicAdd(&dst[q * 8 + 5], (float)p2.h2[1]);
            atomicAdd(&dst[q * 8 + 6], (float)p3.h2[0]);
            atomicAdd(&dst[q * 8 + 7], (float)p3.h2[1]);
        }
    }
    __syncthreads();
    if (t < NPB) {
        int v = v0 + t;
        if (v < n) {
            float di = dinv[v];
            float val[F_OUT];
            float m = -INFINITY;
            #pragma unroll
            for (int c = 0; c < F_OUT; ++c) {
                val[c] = acc[t * 17 + c] * di + b2[c];
                m = fmaxf(m, val[c]);
            }
            float S = 0.f;
            #pragma unroll
            for (int c = 0; c < F_OUT; ++c) S += expf(val[c] - m);
            float L = logf(S) + m;
            #pragma unroll
            for (int c = 0; c < F_OUT; ++c) {
                out_h[(size_t)v * F_OUT + c]  = val[c];
                out_ls[(size_t)v * F_OUT + c] = val[c] - L;
            }
        }
    }
}

extern "C" void kernel_launch(void* const* d_in, const int* in_sizes, int n_in,
                              void* d_out, int out_size, void* d_ws, size_t ws_size,
                              hipStream_t stream) {
    const float* x  = (const float*)d_in[0];
    const int*   ei = (const int*)d_in[1];   // [2,E]: [0:E]=src, [E:2E]=dst
    const float* W1 = (const float*)d_in[2];
    const float* b1 = (const float*)d_in[3];
    const float* W2 = (const float*)d_in[4];
    const float* b2 = (const float*)d_in[5];

    int n  = in_sizes[0] / F_IN;
    int ne = in_sizes[1] / 2;
    int nb = (n + NPB - 1) / NPB;

    float* out_h  = (float*)d_out;
    float* out_ls = out_h + (size_t)n * F_OUT;

    char* p = (char*)d_ws;
    int*      deg    = (int*)p;      p += (size_t)n * sizeof(int);
    float*    dinv   = (float*)p;    p += (size_t)n * sizeof(float);
    int*      bcount = (int*)p;      p += MAX_NB * sizeof(int);
    int*      boff   = (int*)p;      p += (MAX_NB + 4) * sizeof(int);
    int*      bcur   = (int*)p;      p += MAX_NB * sizeof(int);
    uint32_t* ebuf   = (uint32_t*)p; p += (size_t)ne * sizeof(uint32_t);
    uint32_t* g1     = (uint32_t*)p; p += (size_t)n * 16 * sizeof(uint32_t);
    float*    h      = (float*)p;    p += (size_t)n * F_HID * sizeof(float);
    uint32_t* g2     = (uint32_t*)p; p += (size_t)n * 8 * sizeof(uint32_t);

    int m = (n > nb) ? n : nb;
    k_init <<<(m + 255) / 256, 256, 0, stream>>>(deg, bcount, n, nb);
    k_count<<<256, 256, 0, stream>>>(ei, ne, deg, bcount, nb);
    k_dinv <<<(n + 255) / 256, 256, 0, stream>>>(deg, dinv, n);
    k_bscan<<<1, 256, 0, stream>>>(bcount, boff, bcur, nb);
    k_bfill<<<(ne + 255) / 256, 256, 0, stream>>>(ei, ne, bcur, ebuf);

    k_mm1  <<<(n + 7) / 8, 256, 0, stream>>>(x, W1, dinv, g1, n);
    k_agg1 <<<nb, 256, 0, stream>>>(g1, ebuf, boff, dinv, b1, h, n);
    k_mm2  <<<(n + 15) / 16, 256, 0, stream>>>(h, W2, dinv, g2, n);
    k_agg2 <<<nb, 256, 0, stream>>>(g2, ebuf, boff, dinv, b2, out_h, out_ls, n);
}

// Round 5
// 332.211 us; speedup vs baseline: 3.0343x; 3.0343x over previous
//
#include <hip/hip_runtime.h>
#include <hip/hip_bf16.h>
#include <math.h>
#include <stdint.h>

#define F_IN  32
#define F_HID 32
#define F_OUT 16
#define NPB     64     // nodes per bucket
#define LOG_NPB 6
#define MAXNB   2048   // supports n <= 131072
#define BH      256    // histogram/fill blocks

// ---- init: deg=1 (self-loop), totalG=0 ----
__global__ void k_init(int* __restrict__ deg, int* __restrict__ totalG, int n) {
    int i = blockIdx.x * 256 + threadIdx.x;
    if (i < n) deg[i] = 1;
    if (i < MAXNB) totalG[i] = 0;
}

// ---- pass A: per-block bucket histogram + degree count (fused) ----
__global__ void k_hist(const int* __restrict__ ei, int ne, int chunk, int nb,
                       int* __restrict__ deg, int* __restrict__ hist_mat,
                       int* __restrict__ totalG) {
    __shared__ int hist[MAXNB];
    int t = threadIdx.x, b = blockIdx.x;
    for (int i = t; i < nb; i += 256) hist[i] = 0;
    __syncthreads();
    long s = (long)b * chunk;
    long e = s + chunk; if (e > ne) e = ne;
    for (long i = s + t; i < e; i += 256) {
        int dn = ei[ne + i];
        atomicAdd(&deg[dn], 1);
        atomicAdd(&hist[dn >> LOG_NPB], 1);
    }
    __syncthreads();
    for (int i = t; i < nb; i += 256) {
        int v = hist[i];
        hist_mat[(size_t)b * nb + i] = v;
        if (v) atomicAdd(&totalG[i], v);
    }
}

__global__ void k_dinv(const int* __restrict__ deg, float* __restrict__ dinv, int n) {
    int i = blockIdx.x * 256 + threadIdx.x;
    if (i < n) dinv[i] = rsqrtf((float)deg[i]);
}

// ---- exclusive scan of totalG -> boff[0..nb] (single block) ----
__global__ void k_scanb(const int* __restrict__ totalG, int* __restrict__ boff, int nb) {
    __shared__ int sh[256];
    int t = threadIdx.x;
    int base = t * 8;
    int v[8], s = 0;
    #pragma unroll
    for (int j = 0; j < 8; ++j) {
        v[j] = (base + j < nb) ? totalG[base + j] : 0;
        s += v[j];
    }
    sh[t] = s; __syncthreads();
    for (int o = 1; o < 256; o <<= 1) {
        int u = (t >= o) ? sh[t - o] : 0;
        __syncthreads();
        sh[t] += u;
        __syncthreads();
    }
    int run = sh[t] - s;  // exclusive prefix
    #pragma unroll
    for (int j = 0; j < 8; ++j) {
        int k = base + j;
        if (k < nb) { boff[k] = run; run += v[j]; }
    }
    if (t == 255) boff[nb] = sh[255];
}

// ---- column scan: off_mat[b][k] = boff[k] + sum_{b'<b} hist_mat[b'][k] ----
__global__ void k_colscan(const int* __restrict__ boff, const int* __restrict__ hist_mat,
                          int* __restrict__ off_mat, int nb) {
    int k = blockIdx.x * 256 + threadIdx.x;
    if (k >= nb) return;
    int run = boff[k];
    for (int b = 0; b < BH; ++b) {
        size_t idx = (size_t)b * nb + k;
        off_mat[idx] = run;
        run += hist_mat[idx];
    }
}

// ---- pass C: place edges into bucket-grouped ebuf via LDS cursors ----
__global__ void k_fillc(const int* __restrict__ ei, int ne, int chunk, int nb,
                        const int* __restrict__ off_mat, uint32_t* __restrict__ ebuf) {
    __shared__ int cur[MAXNB];
    int t = threadIdx.x, b = blockIdx.x;
    for (int i = t; i < nb; i += 256) cur[i] = off_mat[(size_t)b * nb + i];
    __syncthreads();
    long s = (long)b * chunk;
    long e = s + chunk; if (e > ne) e = ne;
    for (long i = s + t; i < e; i += 256) {
        int sn = ei[i], dn = ei[ne + i];
        int slot = atomicAdd(&cur[dn >> LOG_NPB], 1);
        ebuf[slot] = (uint32_t)sn | ((uint32_t)(dn & (NPB - 1)) << 17);
    }
}

// ---- pass 2: within-bucket sort by node -> csr (src, node-grouped) + off_g ----
__launch_bounds__(256)
__global__ void k_pass2(const uint32_t* __restrict__ ebuf, const int* __restrict__ boff,
                        int* __restrict__ csr, int* __restrict__ off_g, int n) {
    __shared__ int hist[NPB], scn[NPB], cur[NPB];
    int b = blockIdx.x, t = threadIdx.x;
    int base = boff[b], end = boff[b + 1];
    if (t < NPB) hist[t] = 0;
    __syncthreads();
    for (int i = base + t; i < end; i += 256)
        atomicAdd(&hist[(ebuf[i] >> 17) & (NPB - 1)], 1);
    __syncthreads();
    if (t == 0) {
        int run = base;
        for (int l = 0; l < NPB; ++l) { scn[l] = run; cur[l] = run; run += hist[l]; }
    }
    __syncthreads();
    if (t < NPB) {
        int v = (b << LOG_NPB) + t;
        if (v < n) off_g[v] = scn[t];
    }
    for (int i = base + t; i < end; i += 256) {
        uint32_t r = ebuf[i];
        int slot = atomicAdd(&cur[(r >> 17) & (NPB - 1)], 1);
        csr[slot] = (int)(r & 0x1FFFF);
    }
}

// ---- g1 = (x @ W1) * dinv, packed f16x2 (16 words/node) ----
__launch_bounds__(256)
__global__ void k_mm1(const float* __restrict__ x, const float* __restrict__ W1,
                      const float* __restrict__ dinv, uint32_t* __restrict__ g1, int n) {
    __shared__ float Ws[F_IN * F_HID];
    __shared__ float xs[8 * F_IN];
    int t = threadIdx.x;
    for (int i = t; i < F_IN * F_HID; i += 256) Ws[i] = W1[i];
    int nl = t >> 5, c = t & 31;
    int node = blockIdx.x * 8 + nl;
    if (node < n) xs[t] = x[(size_t)node * F_IN + c];
    __syncthreads();
    if (node >= n) return;
    float sum = 0.f;
    #pragma unroll
    for (int k = 0; k < F_IN; ++k) sum += xs[nl * F_IN + k] * Ws[k * F_HID + c];
    float gv = sum * dinv[node];
    float hi = __shfl_xor(gv, 1);
    if ((c & 1) == 0) {
        union { _Float16 h2[2]; uint32_t u; } pk;
        pk.h2[0] = (_Float16)gv; pk.h2[1] = (_Float16)hi;
        g1[(size_t)node * 16 + (c >> 1)] = pk.u;
    }
}

// ---- agg1: gather-sum over CSR, epilogue h = tanh(dinv*s + b1), packed ----
__launch_bounds__(256)
__global__ void k_agg1(const uint32_t* __restrict__ g1, const int* __restrict__ csr,
                       const int* __restrict__ off_g, const int* __restrict__ deg,
                       const float* __restrict__ dinv, const float* __restrict__ b1,
                       uint32_t* __restrict__ h, int n) {
    int t = threadIdx.x, wv = t >> 6, lane = t & 63;
    int v = blockIdx.x * 4 + wv;
    if (v >= n) return;
    int c = lane & 31, slot = lane >> 5;  // 2 edge slots
    int start = off_g[v], cnt = deg[v] - 1;
    float sum = 0.f;
    for (int k = slot; k < cnt; k += 2) {
        int s = csr[start + k];
        union { uint32_t u; _Float16 h2[2]; } p;
        p.u = g1[(size_t)s * 16 + (c >> 1)];
        sum += (float)p.h2[c & 1];
    }
    sum += __shfl_xor(sum, 32);
    {
        union { uint32_t u; _Float16 h2[2]; } p;
        p.u = g1[(size_t)v * 16 + (c >> 1)];
        sum += (float)p.h2[c & 1];  // self-loop
    }
    float hv = tanhf(sum * dinv[v] + b1[c]);
    float hi = __shfl_xor(hv, 1);
    if (slot == 0 && (c & 1) == 0) {
        union { _Float16 h2[2]; uint32_t u; } pk;
        pk.h2[0] = (_Float16)hv; pk.h2[1] = (_Float16)hi;
        h[(size_t)v * 16 + (c >> 1)] = pk.u;
    }
}

// ---- g2 = (h @ W2) * dinv, packed f16x2 (8 words/node) ----
__launch_bounds__(256)
__global__ void k_mm2(const uint32_t* __restrict__ h, const float* __restrict__ W2,
                      const float* __restrict__ dinv, uint32_t* __restrict__ g2, int n) {
    __shared__ float Ws[F_HID * F_OUT];
    __shared__ float hs[16 * F_HID];
    int t = threadIdx.x;
    for (int i = t; i < F_HID * F_OUT; i += 256) Ws[i] = W2[i];
    int node0 = blockIdx.x * 16;
    {
        int nl = t >> 4, cp = t & 15;
        int node = node0 + nl;
        float a = 0.f, bb = 0.f;
        if (node < n) {
            union { uint32_t u; _Float16 h2[2]; } p;
            p.u = h[(size_t)node * 16 + cp];
            a = (float)p.h2[0]; bb = (float)p.h2[1];
        }
        hs[nl * F_HID + 2 * cp]     = a;
        hs[nl * F_HID + 2 * cp + 1] = bb;
    }
    __syncthreads();
    int nl = t >> 4, c = t & 15;
    int node = node0 + nl;
    if (node >= n) return;
    float s = 0.f;
    #pragma unroll
    for (int k = 0; k < F_HID; ++k) s += hs[nl * F_HID + k] * Ws[k * F_OUT + c];
    float gv = s * dinv[node];
    float hi = __shfl_xor(gv, 1);
    if ((c & 1) == 0) {
        union { _Float16 h2[2]; uint32_t u; } pk;
        pk.h2[0] = (_Float16)gv; pk.h2[1] = (_Float16)hi;
        g2[(size_t)node * 8 + (c >> 1)] = pk.u;
    }
}

// ---- agg2: gather-sum + bias + log_softmax (fused final) ----
__launch_bounds__(256)
__global__ void k_agg2(const uint32_t* __restrict__ g2, const int* __restrict__ csr,
                       const int* __restrict__ off_g, const int* __restrict__ deg,
                       const float* __restrict__ dinv, const float* __restrict__ b2,
                       float* __restrict__ out_h, float* __restrict__ out_ls, int n) {
    int t = threadIdx.x, wv = t >> 6, lane = t & 63;
    int v = blockIdx.x * 4 + wv;
    if (v >= n) return;
    int c = lane & 15, slot = lane >> 4;  // 4 edge slots
    int start = off_g[v], cnt = deg[v] - 1;
    float sum = 0.f;
    for (int k = slot; k < cnt; k += 4) {
        int s = csr[start + k];
        union { uint32_t u; _Float16 h2[2]; } p;
        p.u = g2[(size_t)s * 8 + (c >> 1)];
        sum += (float)p.h2[c & 1];
    }
    sum += __shfl_xor(sum, 32);
    sum += __shfl_xor(sum, 16);
    {
        union { uint32_t u; _Float16 h2[2]; } p;
        p.u = g2[(size_t)v * 8 + (c >> 1)];
        sum += (float)p.h2[c & 1];  // self-loop
    }
    float val = sum * dinv[v] + b2[c];
    float m = val;
    #pragma unroll
    for (int o = 8; o >= 1; o >>= 1) m = fmaxf(m, __shfl_xor(m, o));
    float ex = expf(val - m), S = ex;
    #pragma unroll
    for (int o = 8; o >= 1; o >>= 1) S += __shfl_xor(S, o);
    float L = logf(S) + m;
    if (lane < 16) {
        out_h[(size_t)v * F_OUT + c]  = val;
        out_ls[(size_t)v * F_OUT + c] = val - L;
    }
}

extern "C" void kernel_launch(void* const* d_in, const int* in_sizes, int n_in,
                              void* d_out, int out_size, void* d_ws, size_t ws_size,
                              hipStream_t stream) {
    const float* x  = (const float*)d_in[0];
    const int*   ei = (const int*)d_in[1];   // [2,E]: [0:E]=src, [E:2E]=dst
    const float* W1 = (const float*)d_in[2];
    const float* b1 = (const float*)d_in[3];
    const float* W2 = (const float*)d_in[4];
    const float* b2 = (const float*)d_in[5];

    int n  = in_sizes[0] / F_IN;
    int ne = in_sizes[1] / 2;
    int nb = (n + NPB - 1) / NPB;
    int chunk = (ne + BH - 1) / BH;

    float* out_h  = (float*)d_out;
    float* out_ls = out_h + (size_t)n * F_OUT;

    char* p = (char*)d_ws;
    int*      deg      = (int*)p;      p += (size_t)n * sizeof(int);
    float*    dinv     = (float*)p;    p += (size_t)n * sizeof(float);
    int*      totalG   = (int*)p;      p += MAXNB * sizeof(int);
    int*      boff     = (int*)p;      p += (MAXNB + 4) * sizeof(int);
    int*      hist_mat = (int*)p;      p += (size_t)BH * nb * sizeof(int);
    int*      off_mat  = (int*)p;      p += (size_t)BH * nb * sizeof(int);
    uint32_t* ebuf     = (uint32_t*)p; p += (size_t)ne * sizeof(uint32_t);
    int*      csr      = (int*)p;      p += (size_t)ne * sizeof(int);
    int*      off_g    = (int*)p;      p += (size_t)n * sizeof(int);
    uint32_t* g1       = (uint32_t*)p; p += (size_t)n * 16 * sizeof(uint32_t);
    uint32_t* h        = (uint32_t*)p; p += (size_t)n * 16 * sizeof(uint32_t);
    uint32_t* g2       = (uint32_t*)p; p += (size_t)n * 8 * sizeof(uint32_t);

    int m = (n > MAXNB) ? n : MAXNB;
    k_init   <<<(m + 255) / 256, 256, 0, stream>>>(deg, totalG, n);
    k_hist   <<<BH, 256, 0, stream>>>(ei, ne, chunk, nb, deg, hist_mat, totalG);
    k_dinv   <<<(n + 255) / 256, 256, 0, stream>>>(deg, dinv, n);
    k_scanb  <<<1, 256, 0, stream>>>(totalG, boff, nb);
    k_colscan<<<(nb + 255) / 256, 256, 0, stream>>>(boff, hist_mat, off_mat, nb);
    k_fillc  <<<BH, 256, 0, stream>>>(ei, ne, chunk, nb, off_mat, ebuf);
    k_pass2  <<<nb, 256, 0, stream>>>(ebuf, boff, csr, off_g, n);

    k_mm1    <<<(n + 7) / 8, 256, 0, stream>>>(x, W1, dinv, g1, n);
    k_agg1   <<<(n + 3) / 4, 256, 0, stream>>>(g1, csr, off_g, deg, dinv, b1, h, n);
    k_mm2    <<<(n + 15) / 16, 256, 0, stream>>>(h, W2, dinv, g2, n);
    k_agg2   <<<(n + 3) / 4, 256, 0, stream>>>(g2, csr, off_g, deg, dinv, b2, out_h, out_ls, n);
}

// Round 6
// 240.754 us; speedup vs baseline: 4.1870x; 1.3799x over previous
//
#include <hip/hip_runtime.h>
#include <hip/hip_bf16.h>
#include <hip/hip_fp16.h>
#include <math.h>
#include <stdint.h>

#define F_IN  32
#define F_HID 32
#define F_OUT 16
#define NPB     64     // nodes per bucket
#define LOG_NPB 6
#define MAXNB   2048   // supports n <= 131072
#define BH      256    // histogram/fill blocks

__device__ inline uint32_t pk_add(uint32_t a, uint32_t b) {
    union { uint32_t u; __half2 h; } x, y, r;
    x.u = a; y.u = b;
    r.h = __hadd2(x.h, y.h);
    return r.u;
}

// ---- init: deg=1 (self-loop), totalG=0 ----
__global__ void k_init(int* __restrict__ deg, int* __restrict__ totalG, int n) {
    int i = blockIdx.x * 256 + threadIdx.x;
    if (i < n) deg[i] = 1;
    if (i < MAXNB) totalG[i] = 0;
}

// ---- pass A: per-block bucket histogram + degree count (fused) ----
__global__ void k_hist(const int* __restrict__ ei, int ne, int chunk, int nb,
                       int* __restrict__ deg, int* __restrict__ hist_mat,
                       int* __restrict__ totalG) {
    __shared__ int hist[MAXNB];
    int t = threadIdx.x, b = blockIdx.x;
    for (int i = t; i < nb; i += 256) hist[i] = 0;
    __syncthreads();
    long s = (long)b * chunk;
    long e = s + chunk; if (e > ne) e = ne;
    for (long i = s + t; i < e; i += 256) {
        int dn = ei[ne + i];
        atomicAdd(&deg[dn], 1);
        atomicAdd(&hist[dn >> LOG_NPB], 1);
    }
    __syncthreads();
    for (int i = t; i < nb; i += 256) {
        int v = hist[i];
        hist_mat[(size_t)b * nb + i] = v;
        if (v) atomicAdd(&totalG[i], v);
    }
}

__global__ void k_dinv(const int* __restrict__ deg, float* __restrict__ dinv, int n) {
    int i = blockIdx.x * 256 + threadIdx.x;
    if (i < n) dinv[i] = rsqrtf((float)deg[i]);
}

// ---- exclusive scan of totalG -> boff[0..nb] (single block) ----
__global__ void k_scanb(const int* __restrict__ totalG, int* __restrict__ boff, int nb) {
    __shared__ int sh[256];
    int t = threadIdx.x;
    int base = t * 8;
    int v[8], s = 0;
    #pragma unroll
    for (int j = 0; j < 8; ++j) {
        v[j] = (base + j < nb) ? totalG[base + j] : 0;
        s += v[j];
    }
    sh[t] = s; __syncthreads();
    for (int o = 1; o < 256; o <<= 1) {
        int u = (t >= o) ? sh[t - o] : 0;
        __syncthreads();
        sh[t] += u;
        __syncthreads();
    }
    int run = sh[t] - s;  // exclusive prefix
    #pragma unroll
    for (int j = 0; j < 8; ++j) {
        int k = base + j;
        if (k < nb) { boff[k] = run; run += v[j]; }
    }
    if (t == 255) boff[nb] = sh[255];
}

// ---- column scan: off_mat[b][k] = boff[k] + sum_{b'<b} hist_mat[b'][k] ----
__global__ void k_colscan(const int* __restrict__ boff, const int* __restrict__ hist_mat,
                          int* __restrict__ off_mat, int nb) {
    int k = blockIdx.x * 256 + threadIdx.x;
    if (k >= nb) return;
    int run = boff[k];
    for (int b = 0; b < BH; ++b) {
        size_t idx = (size_t)b * nb + k;
        off_mat[idx] = run;
        run += hist_mat[idx];
    }
}

// ---- pass C: place edges into bucket-grouped ebuf via LDS cursors ----
__global__ void k_fillc(const int* __restrict__ ei, int ne, int chunk, int nb,
                        const int* __restrict__ off_mat, uint32_t* __restrict__ ebuf) {
    __shared__ int cur[MAXNB];
    int t = threadIdx.x, b = blockIdx.x;
    for (int i = t; i < nb; i += 256) cur[i] = off_mat[(size_t)b * nb + i];
    __syncthreads();
    long s = (long)b * chunk;
    long e = s + chunk; if (e > ne) e = ne;
    for (long i = s + t; i < e; i += 256) {
        int sn = ei[i], dn = ei[ne + i];
        int slot = atomicAdd(&cur[dn >> LOG_NPB], 1);
        ebuf[slot] = (uint32_t)sn | ((uint32_t)(dn & (NPB - 1)) << 17);
    }
}

// ---- pass 2: within-bucket sort by node -> csr (src, node-grouped) + off_g ----
__launch_bounds__(256)
__global__ void k_pass2(const uint32_t* __restrict__ ebuf, const int* __restrict__ boff,
                        int* __restrict__ csr, int* __restrict__ off_g, int n) {
    __shared__ int hist[NPB], scn[NPB], cur[NPB];
    int b = blockIdx.x, t = threadIdx.x;
    int base = boff[b], end = boff[b + 1];
    if (t < NPB) hist[t] = 0;
    __syncthreads();
    for (int i = base + t; i < end; i += 256)
        atomicAdd(&hist[(ebuf[i] >> 17) & (NPB - 1)], 1);
    __syncthreads();
    if (t == 0) {
        int run = base;
        for (int l = 0; l < NPB; ++l) { scn[l] = run; cur[l] = run; run += hist[l]; }
    }
    __syncthreads();
    if (t < NPB) {
        int v = (b << LOG_NPB) + t;
        if (v < n) off_g[v] = scn[t];
    }
    for (int i = base + t; i < end; i += 256) {
        uint32_t r = ebuf[i];
        int slot = atomicAdd(&cur[(r >> 17) & (NPB - 1)], 1);
        csr[slot] = (int)(r & 0x1FFFF);
    }
}

// ---- g1 = (x @ W1) * dinv, packed f16x2 (16 words/node) ----
__launch_bounds__(256)
__global__ void k_mm1(const float* __restrict__ x, const float* __restrict__ W1,
                      const float* __restrict__ dinv, uint32_t* __restrict__ g1, int n) {
    __shared__ float Ws[F_IN * F_HID];
    __shared__ float xs[8 * F_IN];
    int t = threadIdx.x;
    for (int i = t; i < F_IN * F_HID; i += 256) Ws[i] = W1[i];
    int nl = t >> 5, c = t & 31;
    int node = blockIdx.x * 8 + nl;
    if (node < n) xs[t] = x[(size_t)node * F_IN + c];
    __syncthreads();
    if (node >= n) return;
    float sum = 0.f;
    #pragma unroll
    for (int k = 0; k < F_IN; ++k) sum += xs[nl * F_IN + k] * Ws[k * F_HID + c];
    float gv = sum * dinv[node];
    float hi = __shfl_xor(gv, 1);
    if ((c & 1) == 0) {
        union { __half2 h; uint32_t u; } pk;
        pk.h = __floats2half2_rn(gv, hi);
        g1[(size_t)node * 16 + (c >> 1)] = pk.u;
    }
}

// ---- agg1: wave/node, 16 edge slots x uint4(16B) lanes; pk_add accumulate ----
// epilogue h = tanh(dinv*s + b1), packed f16x2
__launch_bounds__(256)
__global__ void k_agg1(const uint32_t* __restrict__ g1, const int* __restrict__ csr,
                       const int* __restrict__ off_g, const int* __restrict__ deg,
                       const float* __restrict__ dinv, const float* __restrict__ b1,
                       uint32_t* __restrict__ h, int n) {
    int t = threadIdx.x, wv = t >> 6, lane = t & 63;
    int v = blockIdx.x * 4 + wv;
    if (v >= n) return;
    int q = lane & 3, slot = lane >> 2;  // 16 edge slots, 4 lanes x 16B per row
    int start = off_g[v], cnt = deg[v] - 1;
    uint4 acc;
    if (slot == 0) acc = *(const uint4*)(g1 + (size_t)v * 16 + q * 4);  // self-loop
    else acc = make_uint4(0u, 0u, 0u, 0u);
    for (int k = slot; k < cnt; k += 16) {
        int s = csr[start + k];
        uint4 w = *(const uint4*)(g1 + (size_t)s * 16 + q * 4);
        acc.x = pk_add(acc.x, w.x);
        acc.y = pk_add(acc.y, w.y);
        acc.z = pk_add(acc.z, w.z);
        acc.w = pk_add(acc.w, w.w);
    }
    #pragma unroll
    for (int off = 4; off < 64; off <<= 1) {
        acc.x = pk_add(acc.x, (uint32_t)__shfl_xor((int)acc.x, off));
        acc.y = pk_add(acc.y, (uint32_t)__shfl_xor((int)acc.y, off));
        acc.z = pk_add(acc.z, (uint32_t)__shfl_xor((int)acc.z, off));
        acc.w = pk_add(acc.w, (uint32_t)__shfl_xor((int)acc.w, off));
    }
    if (slot == 0) {
        float di = dinv[v];
        float4 bA = *(const float4*)(b1 + 8 * q);
        float4 bB = *(const float4*)(b1 + 8 * q + 4);
        union { uint32_t u; __half2 h; } w0, w1, w2, w3;
        w0.u = acc.x; w1.u = acc.y; w2.u = acc.z; w3.u = acc.w;
        float2 f0 = __half22float2(w0.h), f1 = __half22float2(w1.h);
        float2 f2 = __half22float2(w2.h), f3 = __half22float2(w3.h);
        float h0 = tanhf(f0.x * di + bA.x), h1 = tanhf(f0.y * di + bA.y);
        float h2 = tanhf(f1.x * di + bA.z), h3 = tanhf(f1.y * di + bA.w);
        float h4 = tanhf(f2.x * di + bB.x), h5 = tanhf(f2.y * di + bB.y);
        float h6 = tanhf(f3.x * di + bB.z), h7 = tanhf(f3.y * di + bB.w);
        union { __half2 h; uint32_t u; } o0, o1, o2, o3;
        o0.h = __floats2half2_rn(h0, h1);
        o1.h = __floats2half2_rn(h2, h3);
        o2.h = __floats2half2_rn(h4, h5);
        o3.h = __floats2half2_rn(h6, h7);
        *(uint4*)(h + (size_t)v * 16 + q * 4) = make_uint4(o0.u, o1.u, o2.u, o3.u);
    }
}

// ---- g2 = (h @ W2) * dinv, packed f16x2 (8 words/node) ----
__launch_bounds__(256)
__global__ void k_mm2(const uint32_t* __restrict__ h, const float* __restrict__ W2,
                      const float* __restrict__ dinv, uint32_t* __restrict__ g2, int n) {
    __shared__ float Ws[F_HID * F_OUT];
    __shared__ float hs[16 * F_HID];
    int t = threadIdx.x;
    for (int i = t; i < F_HID * F_OUT; i += 256) Ws[i] = W2[i];
    int node0 = blockIdx.x * 16;
    {
        int nl = t >> 4, cp = t & 15;
        int node = node0 + nl;
        float a = 0.f, bb = 0.f;
        if (node < n) {
            union { uint32_t u; __half2 h; } p;
            p.u = h[(size_t)node * 16 + cp];
            float2 f = __half22float2(p.h);
            a = f.x; bb = f.y;
        }
        hs[nl * F_HID + 2 * cp]     = a;
        hs[nl * F_HID + 2 * cp + 1] = bb;
    }
    __syncthreads();
    int nl = t >> 4, c = t & 15;
    int node = node0 + nl;
    if (node >= n) return;
    float s = 0.f;
    #pragma unroll
    for (int k = 0; k < F_HID; ++k) s += hs[nl * F_HID + k] * Ws[k * F_OUT + c];
    float gv = s * dinv[node];
    float hi = __shfl_xor(gv, 1);
    if ((c & 1) == 0) {
        union { __half2 h; uint32_t u; } pk;
        pk.h = __floats2half2_rn(gv, hi);
        g2[(size_t)node * 8 + (c >> 1)] = pk.u;
    }
}

// ---- agg2: wave/node, 16 edge slots x uint2(8B) lanes; fused log_softmax ----
__launch_bounds__(256)
__global__ void k_agg2(const uint32_t* __restrict__ g2, const int* __restrict__ csr,
                       const int* __restrict__ off_g, const int* __restrict__ deg,
                       const float* __restrict__ dinv, const float* __restrict__ b2,
                       float* __restrict__ out_h, float* __restrict__ out_ls, int n) {
    int t = threadIdx.x, wv = t >> 6, lane = t & 63;
    int v = blockIdx.x * 4 + wv;
    if (v >= n) return;
    int q = lane & 3, slot = lane >> 2;  // 16 slots, 4 lanes x 8B per 32B row
    int start = off_g[v], cnt = deg[v] - 1;
    uint2 acc;
    if (slot == 0) acc = *(const uint2*)(g2 + (size_t)v * 8 + q * 2);  // self-loop
    else acc = make_uint2(0u, 0u);
    for (int k = slot; k < cnt; k += 16) {
        int s = csr[start + k];
        uint2 w = *(const uint2*)(g2 + (size_t)s * 8 + q * 2);
        acc.x = pk_add(acc.x, w.x);
        acc.y = pk_add(acc.y, w.y);
    }
    #pragma unroll
    for (int off = 4; off < 64; off <<= 1) {
        acc.x = pk_add(acc.x, (uint32_t)__shfl_xor((int)acc.x, off));
        acc.y = pk_add(acc.y, (uint32_t)__shfl_xor((int)acc.y, off));
    }
    if (slot == 0) {
        float di = dinv[v];
        float4 bb = *(const float4*)(b2 + 4 * q);
        union { uint32_t u; __half2 h; } w0, w1;
        w0.u = acc.x; w1.u = acc.y;
        float2 f0 = __half22float2(w0.h), f1 = __half22float2(w1.h);
        float val0 = f0.x * di + bb.x, val1 = f0.y * di + bb.y;
        float val2 = f1.x * di + bb.z, val3 = f1.y * di + bb.w;
        float m = fmaxf(fmaxf(val0, val1), fmaxf(val2, val3));
        m = fmaxf(m, __shfl_xor(m, 1));
        m = fmaxf(m, __shfl_xor(m, 2));
        float S = expf(val0 - m) + expf(val1 - m) + expf(val2 - m) + expf(val3 - m);
        S += __shfl_xor(S, 1);
        S += __shfl_xor(S, 2);
        float L = logf(S) + m;
        *(float4*)(out_h + (size_t)v * F_OUT + 4 * q) =
            make_float4(val0, val1, val2, val3);
        *(float4*)(out_ls + (size_t)v * F_OUT + 4 * q) =
            make_float4(val0 - L, val1 - L, val2 - L, val3 - L);
    }
}

extern "C" void kernel_launch(void* const* d_in, const int* in_sizes, int n_in,
                              void* d_out, int out_size, void* d_ws, size_t ws_size,
                              hipStream_t stream) {
    const float* x  = (const float*)d_in[0];
    const int*   ei = (const int*)d_in[1];   // [2,E]: [0:E]=src, [E:2E]=dst
    const float* W1 = (const float*)d_in[2];
    const float* b1 = (const float*)d_in[3];
    const float* W2 = (const float*)d_in[4];
    const float* b2 = (const float*)d_in[5];

    int n  = in_sizes[0] / F_IN;
    int ne = in_sizes[1] / 2;
    int nb = (n + NPB - 1) / NPB;
    int chunk = (ne + BH - 1) / BH;

    float* out_h  = (float*)d_out;
    float* out_ls = out_h + (size_t)n * F_OUT;

    char* p = (char*)d_ws;
    int*      deg      = (int*)p;      p += (size_t)n * sizeof(int);
    float*    dinv     = (float*)p;    p += (size_t)n * sizeof(float);
    int*      totalG   = (int*)p;      p += MAXNB * sizeof(int);
    int*      boff     = (int*)p;      p += (MAXNB + 4) * sizeof(int);
    int*      hist_mat = (int*)p;      p += (size_t)BH * nb * sizeof(int);
    int*      off_mat  = (int*)p;      p += (size_t)BH * nb * sizeof(int);
    uint32_t* ebuf     = (uint32_t*)p; p += (size_t)ne * sizeof(uint32_t);
    int*      csr      = (int*)p;      p += (size_t)ne * sizeof(int);
    int*      off_g    = (int*)p;      p += (size_t)n * sizeof(int);
    uint32_t* g1       = (uint32_t*)p; p += (size_t)n * 16 * sizeof(uint32_t);
    uint32_t* h        = (uint32_t*)p; p += (size_t)n * 16 * sizeof(uint32_t);
    uint32_t* g2       = (uint32_t*)p; p += (size_t)n * 8 * sizeof(uint32_t);

    int m = (n > MAXNB) ? n : MAXNB;
    k_init   <<<(m + 255) / 256, 256, 0, stream>>>(deg, totalG, n);
    k_hist   <<<BH, 256, 0, stream>>>(ei, ne, chunk, nb, deg, hist_mat, totalG);
    k_dinv   <<<(n + 255) / 256, 256, 0, stream>>>(deg, dinv, n);
    k_scanb  <<<1, 256, 0, stream>>>(totalG, boff, nb);
    k_colscan<<<(nb + 255) / 256, 256, 0, stream>>>(boff, hist_mat, off_mat, nb);
    k_fillc  <<<BH, 256, 0, stream>>>(ei, ne, chunk, nb, off_mat, ebuf);
    k_pass2  <<<nb, 256, 0, stream>>>(ebuf, boff, csr, off_g, n);

    k_mm1    <<<(n + 7) / 8, 256, 0, stream>>>(x, W1, dinv, g1, n);
    k_agg1   <<<(n + 3) / 4, 256, 0, stream>>>(g1, csr, off_g, deg, dinv, b1, h, n);
    k_mm2    <<<(n + 15) / 16, 256, 0, stream>>>(h, W2, dinv, g2, n);
    k_agg2   <<<(n + 3) / 4, 256, 0, stream>>>(g2, csr, off_g, deg, dinv, b2, out_h, out_ls, n);
}

// Round 7
// 167.163 us; speedup vs baseline: 6.0302x; 1.4402x over previous
//
#include <hip/hip_runtime.h>
#include <hip/hip_bf16.h>
#include <hip/hip_fp16.h>
#include <math.h>
#include <stdint.h>

#define F_IN  32
#define F_HID 32
#define F_OUT 16
#define NPB     64     // nodes per bucket
#define LOG_NPB 6
#define MAXNB   2048   // supports n <= 131072
#define BH      256    // histogram/fill blocks

__device__ inline uint32_t pk_add(uint32_t a, uint32_t b) {
    union { uint32_t u; __half2 h; } x, y, r;
    x.u = a; y.u = b;
    r.h = __hadd2(x.h, y.h);
    return r.u;
}

// ---- init: totalG=0 ----
__global__ void k_init(int* __restrict__ totalG) {
    int i = blockIdx.x * 256 + threadIdx.x;
    if (i < MAXNB) totalG[i] = 0;
}

// ---- pass A: per-block bucket histogram (NO global deg atomics) ----
__launch_bounds__(1024)
__global__ void k_hist(const int* __restrict__ ei, int ne, int chunk, int nb,
                       int* __restrict__ hist_mat, int* __restrict__ totalG) {
    __shared__ int hist[MAXNB];
    int t = threadIdx.x, b = blockIdx.x;
    for (int i = t; i < nb; i += 1024) hist[i] = 0;
    __syncthreads();
    long s = (long)b * chunk;
    long e = s + chunk; if (e > ne) e = ne;
    for (long i = s + t; i < e; i += 1024)
        atomicAdd(&hist[ei[ne + i] >> LOG_NPB], 1);
    __syncthreads();
    for (int i = t; i < nb; i += 1024) {
        int v = hist[i];
        hist_mat[(size_t)b * nb + i] = v;
        if (v) atomicAdd(&totalG[i], v);
    }
}

// ---- exclusive scan of totalG -> boff[0..nb] (single block) ----
__global__ void k_scanb(const int* __restrict__ totalG, int* __restrict__ boff, int nb) {
    __shared__ int sh[256];
    int t = threadIdx.x;
    int base = t * 8;
    int v[8], s = 0;
    #pragma unroll
    for (int j = 0; j < 8; ++j) {
        v[j] = (base + j < nb) ? totalG[base + j] : 0;
        s += v[j];
    }
    sh[t] = s; __syncthreads();
    for (int o = 1; o < 256; o <<= 1) {
        int u = (t >= o) ? sh[t - o] : 0;
        __syncthreads();
        sh[t] += u;
        __syncthreads();
    }
    int run = sh[t] - s;  // exclusive prefix
    #pragma unroll
    for (int j = 0; j < 8; ++j) {
        int k = base + j;
        if (k < nb) { boff[k] = run; run += v[j]; }
    }
    if (t == 255) boff[nb] = sh[255];
}

// ---- column scan: off_mat[b][k] = boff[k] + sum_{b'<b} hist_mat[b'][k] ----
__global__ void k_colscan(const int* __restrict__ boff, const int* __restrict__ hist_mat,
                          int* __restrict__ off_mat, int nb) {
    int k = blockIdx.x * 256 + threadIdx.x;
    if (k >= nb) return;
    int run = boff[k];
    #pragma unroll 8
    for (int b = 0; b < BH; ++b) {
        size_t idx = (size_t)b * nb + k;
        off_mat[idx] = run;
        run += hist_mat[idx];
    }
}

// ---- pass C: place edges into bucket-grouped ebuf via LDS cursors ----
__launch_bounds__(1024)
__global__ void k_fillc(const int* __restrict__ ei, int ne, int chunk, int nb,
                        const int* __restrict__ off_mat, uint32_t* __restrict__ ebuf) {
    __shared__ int cur[MAXNB];
    int t = threadIdx.x, b = blockIdx.x;
    for (int i = t; i < nb; i += 1024) cur[i] = off_mat[(size_t)b * nb + i];
    __syncthreads();
    long s = (long)b * chunk;
    long e = s + chunk; if (e > ne) e = ne;
    for (long i = s + t; i < e; i += 1024) {
        int sn = ei[i], dn = ei[ne + i];
        int slot = atomicAdd(&cur[dn >> LOG_NPB], 1);
        ebuf[slot] = (uint32_t)sn | ((uint32_t)(dn & (NPB - 1)) << 17);
    }
}

// ---- pass 2: within-bucket sort -> csr + off_g (n+1 entries) + dinv ----
__launch_bounds__(256)
__global__ void k_pass2(const uint32_t* __restrict__ ebuf, const int* __restrict__ boff,
                        int* __restrict__ csr, int* __restrict__ off_g,
                        float* __restrict__ dinv, int n, int nb) {
    __shared__ int hist[NPB], scn[NPB], cur[NPB];
    int b = blockIdx.x, t = threadIdx.x;
    int base = boff[b], end = boff[b + 1];
    if (t < NPB) hist[t] = 0;
    __syncthreads();
    for (int i = base + t; i < end; i += 256)
        atomicAdd(&hist[(ebuf[i] >> 17) & (NPB - 1)], 1);
    __syncthreads();
    if (t == 0) {
        int run = base;
        for (int l = 0; l < NPB; ++l) { scn[l] = run; cur[l] = run; run += hist[l]; }
    }
    __syncthreads();
    if (t < NPB) {
        int v = (b << LOG_NPB) + t;
        if (v < n) {
            off_g[v] = scn[t];
            dinv[v] = rsqrtf((float)(hist[t] + 1));  // +1 self-loop
        }
    }
    if (b == nb - 1 && t == 0) off_g[n] = end;
    for (int i = base + t; i < end; i += 256) {
        uint32_t r = ebuf[i];
        int slot = atomicAdd(&cur[(r >> 17) & (NPB - 1)], 1);
        csr[slot] = (int)(r & 0x1FFFF);
    }
}

// ---- g1 = (x @ W1) * dinv, packed f16x2 (16 words/node) ----
__launch_bounds__(256)
__global__ void k_mm1(const float* __restrict__ x, const float* __restrict__ W1,
                      const float* __restrict__ dinv, uint32_t* __restrict__ g1, int n) {
    __shared__ float Ws[F_IN * F_HID];
    __shared__ float xs[8 * F_IN];
    int t = threadIdx.x;
    for (int i = t; i < F_IN * F_HID; i += 256) Ws[i] = W1[i];
    int nl = t >> 5, c = t & 31;
    int node = blockIdx.x * 8 + nl;
    if (node < n) xs[t] = x[(size_t)node * F_IN + c];
    __syncthreads();
    if (node >= n) return;
    float sum = 0.f;
    #pragma unroll
    for (int k = 0; k < F_IN; ++k) sum += xs[nl * F_IN + k] * Ws[k * F_HID + c];
    float gv = sum * dinv[node];
    float hi = __shfl_xor(gv, 1);
    if ((c & 1) == 0) {
        union { __half2 h; uint32_t u; } pk;
        pk.h = __floats2half2_rn(gv, hi);
        g1[(size_t)node * 16 + (c >> 1)] = pk.u;
    }
}

// ---- agg1: wave/node, 16 edge slots x uint4(16B) lanes; pk_add accumulate ----
__launch_bounds__(256)
__global__ void k_agg1(const uint32_t* __restrict__ g1, const int* __restrict__ csr,
                       const int* __restrict__ off_g,
                       const float* __restrict__ dinv, const float* __restrict__ b1,
                       uint32_t* __restrict__ h, int n) {
    int t = threadIdx.x, wv = t >> 6, lane = t & 63;
    int v = blockIdx.x * 4 + wv;
    if (v >= n) return;
    int q = lane & 3, slot = lane >> 2;  // 16 edge slots, 4 lanes x 16B per row
    int start = off_g[v], cnt = off_g[v + 1] - start;
    uint4 acc;
    if (slot == 0) acc = *(const uint4*)(g1 + (size_t)v * 16 + q * 4);  // self-loop
    else acc = make_uint4(0u, 0u, 0u, 0u);
    for (int k = slot; k < cnt; k += 16) {
        int s = csr[start + k];
        uint4 w = *(const uint4*)(g1 + (size_t)s * 16 + q * 4);
        acc.x = pk_add(acc.x, w.x);
        acc.y = pk_add(acc.y, w.y);
        acc.z = pk_add(acc.z, w.z);
        acc.w = pk_add(acc.w, w.w);
    }
    #pragma unroll
    for (int off = 4; off < 64; off <<= 1) {
        acc.x = pk_add(acc.x, (uint32_t)__shfl_xor((int)acc.x, off));
        acc.y = pk_add(acc.y, (uint32_t)__shfl_xor((int)acc.y, off));
        acc.z = pk_add(acc.z, (uint32_t)__shfl_xor((int)acc.z, off));
        acc.w = pk_add(acc.w, (uint32_t)__shfl_xor((int)acc.w, off));
    }
    if (slot == 0) {
        float di = dinv[v];
        float4 bA = *(const float4*)(b1 + 8 * q);
        float4 bB = *(const float4*)(b1 + 8 * q + 4);
        union { uint32_t u; __half2 h; } w0, w1, w2, w3;
        w0.u = acc.x; w1.u = acc.y; w2.u = acc.z; w3.u = acc.w;
        float2 f0 = __half22float2(w0.h), f1 = __half22float2(w1.h);
        float2 f2 = __half22float2(w2.h), f3 = __half22float2(w3.h);
        float h0 = tanhf(f0.x * di + bA.x), h1 = tanhf(f0.y * di + bA.y);
        float h2 = tanhf(f1.x * di + bA.z), h3 = tanhf(f1.y * di + bA.w);
        float h4 = tanhf(f2.x * di + bB.x), h5 = tanhf(f2.y * di + bB.y);
        float h6 = tanhf(f3.x * di + bB.z), h7 = tanhf(f3.y * di + bB.w);
        union { __half2 h; uint32_t u; } o0, o1, o2, o3;
        o0.h = __floats2half2_rn(h0, h1);
        o1.h = __floats2half2_rn(h2, h3);
        o2.h = __floats2half2_rn(h4, h5);
        o3.h = __floats2half2_rn(h6, h7);
        *(uint4*)(h + (size_t)v * 16 + q * 4) = make_uint4(o0.u, o1.u, o2.u, o3.u);
    }
}

// ---- g2 = (h @ W2) * dinv, packed f16x2 (8 words/node) ----
__launch_bounds__(256)
__global__ void k_mm2(const uint32_t* __restrict__ h, const float* __restrict__ W2,
                      const float* __restrict__ dinv, uint32_t* __restrict__ g2, int n) {
    __shared__ float Ws[F_HID * F_OUT];
    __shared__ float hs[16 * F_HID];
    int t = threadIdx.x;
    for (int i = t; i < F_HID * F_OUT; i += 256) Ws[i] = W2[i];
    int node0 = blockIdx.x * 16;
    {
        int nl = t >> 4, cp = t & 15;
        int node = node0 + nl;
        float a = 0.f, bb = 0.f;
        if (node < n) {
            union { uint32_t u; __half2 h; } p;
            p.u = h[(size_t)node * 16 + cp];
            float2 f = __half22float2(p.h);
            a = f.x; bb = f.y;
        }
        hs[nl * F_HID + 2 * cp]     = a;
        hs[nl * F_HID + 2 * cp + 1] = bb;
    }
    __syncthreads();
    int nl = t >> 4, c = t & 15;
    int node = node0 + nl;
    if (node >= n) return;
    float s = 0.f;
    #pragma unroll
    for (int k = 0; k < F_HID; ++k) s += hs[nl * F_HID + k] * Ws[k * F_OUT + c];
    float gv = s * dinv[node];
    float hi = __shfl_xor(gv, 1);
    if ((c & 1) == 0) {
        union { __half2 h; uint32_t u; } pk;
        pk.h = __floats2half2_rn(gv, hi);
        g2[(size_t)node * 8 + (c >> 1)] = pk.u;
    }
}

// ---- agg2: wave/node, 16 edge slots x uint2(8B) lanes; fused log_softmax ----
__launch_bounds__(256)
__global__ void k_agg2(const uint32_t* __restrict__ g2, const int* __restrict__ csr,
                       const int* __restrict__ off_g,
                       const float* __restrict__ dinv, const float* __restrict__ b2,
                       float* __restrict__ out_h, float* __restrict__ out_ls, int n) {
    int t = threadIdx.x, wv = t >> 6, lane = t & 63;
    int v = blockIdx.x * 4 + wv;
    if (v >= n) return;
    int q = lane & 3, slot = lane >> 2;  // 16 slots, 4 lanes x 8B per 32B row
    int start = off_g[v], cnt = off_g[v + 1] - start;
    uint2 acc;
    if (slot == 0) acc = *(const uint2*)(g2 + (size_t)v * 8 + q * 2);  // self-loop
    else acc = make_uint2(0u, 0u);
    for (int k = slot; k < cnt; k += 16) {
        int s = csr[start + k];
        uint2 w = *(const uint2*)(g2 + (size_t)s * 8 + q * 2);
        acc.x = pk_add(acc.x, w.x);
        acc.y = pk_add(acc.y, w.y);
    }
    #pragma unroll
    for (int off = 4; off < 64; off <<= 1) {
        acc.x = pk_add(acc.x, (uint32_t)__shfl_xor((int)acc.x, off));
        acc.y = pk_add(acc.y, (uint32_t)__shfl_xor((int)acc.y, off));
    }
    if (slot == 0) {
        float di = dinv[v];
        float4 bb = *(const float4*)(b2 + 4 * q);
        union { uint32_t u; __half2 h; } w0, w1;
        w0.u = acc.x; w1.u = acc.y;
        float2 f0 = __half22float2(w0.h), f1 = __half22float2(w1.h);
        float val0 = f0.x * di + bb.x, val1 = f0.y * di + bb.y;
        float val2 = f1.x * di + bb.z, val3 = f1.y * di + bb.w;
        float m = fmaxf(fmaxf(val0, val1), fmaxf(val2, val3));
        m = fmaxf(m, __shfl_xor(m, 1));
        m = fmaxf(m, __shfl_xor(m, 2));
        float S = expf(val0 - m) + expf(val1 - m) + expf(val2 - m) + expf(val3 - m);
        S += __shfl_xor(S, 1);
        S += __shfl_xor(S, 2);
        float L = logf(S) + m;
        *(float4*)(out_h + (size_t)v * F_OUT + 4 * q) =
            make_float4(val0, val1, val2, val3);
        *(float4*)(out_ls + (size_t)v * F_OUT + 4 * q) =
            make_float4(val0 - L, val1 - L, val2 - L, val3 - L);
    }
}

extern "C" void kernel_launch(void* const* d_in, const int* in_sizes, int n_in,
                              void* d_out, int out_size, void* d_ws, size_t ws_size,
                              hipStream_t stream) {
    const float* x  = (const float*)d_in[0];
    const int*   ei = (const int*)d_in[1];   // [2,E]: [0:E]=src, [E:2E]=dst
    const float* W1 = (const float*)d_in[2];
    const float* b1 = (const float*)d_in[3];
    const float* W2 = (const float*)d_in[4];
    const float* b2 = (const float*)d_in[5];

    int n  = in_sizes[0] / F_IN;
    int ne = in_sizes[1] / 2;
    int nb = (n + NPB - 1) / NPB;
    int chunk = (ne + BH - 1) / BH;

    float* out_h  = (float*)d_out;
    float* out_ls = out_h + (size_t)n * F_OUT;

    char* p = (char*)d_ws;
    float*    dinv     = (float*)p;    p += (size_t)n * sizeof(float);
    int*      totalG   = (int*)p;      p += MAXNB * sizeof(int);
    int*      boff     = (int*)p;      p += (MAXNB + 4) * sizeof(int);
    int*      off_g    = (int*)p;      p += ((size_t)n + 4) * sizeof(int);
    int*      hist_mat = (int*)p;      p += (size_t)BH * nb * sizeof(int);
    int*      off_mat  = (int*)p;      p += (size_t)BH * nb * sizeof(int);
    uint32_t* ebuf     = (uint32_t*)p; p += (size_t)ne * sizeof(uint32_t);
    int*      csr      = (int*)p;      p += (size_t)ne * sizeof(int);
    uint32_t* g1       = (uint32_t*)p; p += (size_t)n * 16 * sizeof(uint32_t);
    uint32_t* h        = (uint32_t*)p; p += (size_t)n * 16 * sizeof(uint32_t);
    uint32_t* g2       = (uint32_t*)p; p += (size_t)n * 8 * sizeof(uint32_t);

    k_init   <<<(MAXNB + 255) / 256, 256, 0, stream>>>(totalG);
    k_hist   <<<BH, 1024, 0, stream>>>(ei, ne, chunk, nb, hist_mat, totalG);
    k_scanb  <<<1, 256, 0, stream>>>(totalG, boff, nb);
    k_colscan<<<(nb + 255) / 256, 256, 0, stream>>>(boff, hist_mat, off_mat, nb);
    k_fillc  <<<BH, 1024, 0, stream>>>(ei, ne, chunk, nb, off_mat, ebuf);
    k_pass2  <<<nb, 256, 0, stream>>>(ebuf, boff, csr, off_g, dinv, n, nb);

    k_mm1    <<<(n + 7) / 8, 256, 0, stream>>>(x, W1, dinv, g1, n);
    k_agg1   <<<(n + 3) / 4, 256, 0, stream>>>(g1, csr, off_g, dinv, b1, h, n);
    k_mm2    <<<(n + 15) / 16, 256, 0, stream>>>(h, W2, dinv, g2, n);
    k_agg2   <<<(n + 3) / 4, 256, 0, stream>>>(g2, csr, off_g, dinv, b2, out_h, out_ls, n);
}

// Round 8
// 138.085 us; speedup vs baseline: 7.3001x; 1.2106x over previous
//
#include <hip/hip_runtime.h>
#include <hip/hip_bf16.h>
#include <hip/hip_fp16.h>
#include <math.h>
#include <stdint.h>

#define F_IN  32
#define F_HID 32
#define F_OUT 16
#define NPB     64     // nodes per bucket
#define LOG_NPB 6
#define MAXNB   2048   // supports n <= 131072
#define BH      256    // histogram/fill blocks

__device__ inline uint32_t pk_add(uint32_t a, uint32_t b) {
    union { uint32_t u; __half2 h; } x, y, r;
    x.u = a; y.u = b;
    r.h = __hadd2(x.h, y.h);
    return r.u;
}

__device__ inline float fexp(float x) {           // e^x
    return __builtin_amdgcn_exp2f(x * 1.44269504089f);
}
__device__ inline float ftanh(float x) {          // tanh via exp2+rcp
    x = fminf(fmaxf(x, -15.f), 15.f);
    float t = __builtin_amdgcn_exp2f(x * 2.88539008178f);  // e^(2x)
    return (t - 1.0f) * __builtin_amdgcn_rcpf(t + 1.0f);
}

// ---- init: totalG=0 ----
__global__ void k_init(int* __restrict__ totalG) {
    int i = blockIdx.x * 256 + threadIdx.x;
    if (i < MAXNB) totalG[i] = 0;
}

// ---- pass A: per-block bucket histogram ----
__launch_bounds__(1024)
__global__ void k_hist(const int* __restrict__ ei, int ne, int chunk, int nb,
                       int* __restrict__ hist_mat, int* __restrict__ totalG) {
    __shared__ int hist[MAXNB];
    int t = threadIdx.x, b = blockIdx.x;
    for (int i = t; i < nb; i += 1024) hist[i] = 0;
    __syncthreads();
    long s = (long)b * chunk;
    long e = s + chunk; if (e > ne) e = ne;
    for (long i = s + t; i < e; i += 1024)
        atomicAdd(&hist[ei[ne + i] >> LOG_NPB], 1);
    __syncthreads();
    for (int i = t; i < nb; i += 1024) {
        int v = hist[i];
        hist_mat[(size_t)b * nb + i] = v;
        if (v) atomicAdd(&totalG[i], v);
    }
}

// ---- exclusive scan of totalG -> boff[0..nb] (single block) ----
__global__ void k_scanb(const int* __restrict__ totalG, int* __restrict__ boff, int nb) {
    __shared__ int sh[256];
    int t = threadIdx.x;
    int base = t * 8;
    int v[8], s = 0;
    #pragma unroll
    for (int j = 0; j < 8; ++j) {
        v[j] = (base + j < nb) ? totalG[base + j] : 0;
        s += v[j];
    }
    sh[t] = s; __syncthreads();
    for (int o = 1; o < 256; o <<= 1) {
        int u = (t >= o) ? sh[t - o] : 0;
        __syncthreads();
        sh[t] += u;
        __syncthreads();
    }
    int run = sh[t] - s;  // exclusive prefix
    #pragma unroll
    for (int j = 0; j < 8; ++j) {
        int k = base + j;
        if (k < nb) { boff[k] = run; run += v[j]; }
    }
    if (t == 255) boff[nb] = sh[255];
}

// ---- column scan: off_mat[b][k] = boff[k] + sum_{b'<b} hist_mat[b'][k] ----
__global__ void k_colscan(const int* __restrict__ boff, const int* __restrict__ hist_mat,
                          int* __restrict__ off_mat, int nb) {
    int k = blockIdx.x * 256 + threadIdx.x;
    if (k >= nb) return;
    int run = boff[k];
    #pragma unroll 8
    for (int b = 0; b < BH; ++b) {
        size_t idx = (size_t)b * nb + k;
        off_mat[idx] = run;
        run += hist_mat[idx];
    }
}

// ---- pass C: place edges into bucket-grouped ebuf via LDS cursors ----
__launch_bounds__(1024)
__global__ void k_fillc(const int* __restrict__ ei, int ne, int chunk, int nb,
                        const int* __restrict__ off_mat, uint32_t* __restrict__ ebuf) {
    __shared__ int cur[MAXNB];
    int t = threadIdx.x, b = blockIdx.x;
    for (int i = t; i < nb; i += 1024) cur[i] = off_mat[(size_t)b * nb + i];
    __syncthreads();
    long s = (long)b * chunk;
    long e = s + chunk; if (e > ne) e = ne;
    for (long i = s + t; i < e; i += 1024) {
        int sn = ei[i], dn = ei[ne + i];
        int slot = atomicAdd(&cur[dn >> LOG_NPB], 1);
        ebuf[slot] = (uint32_t)sn | ((uint32_t)(dn & (NPB - 1)) << 17);
    }
}

// ---- pass 2: within-bucket sort -> csr + off_g (n+1 entries) + dinv ----
__launch_bounds__(256)
__global__ void k_pass2(const uint32_t* __restrict__ ebuf, const int* __restrict__ boff,
                        int* __restrict__ csr, int* __restrict__ off_g,
                        float* __restrict__ dinv, int n, int nb) {
    __shared__ int hist[NPB], scn[NPB], cur[NPB];
    int b = blockIdx.x, t = threadIdx.x;
    int base = boff[b], end = boff[b + 1];
    if (t < NPB) hist[t] = 0;
    __syncthreads();
    for (int i = base + t; i < end; i += 256)
        atomicAdd(&hist[(ebuf[i] >> 17) & (NPB - 1)], 1);
    __syncthreads();
    if (t == 0) {
        int run = base;
        for (int l = 0; l < NPB; ++l) { scn[l] = run; cur[l] = run; run += hist[l]; }
    }
    __syncthreads();
    if (t < NPB) {
        int v = (b << LOG_NPB) + t;
        if (v < n) {
            off_g[v] = scn[t];
            dinv[v] = rsqrtf((float)(hist[t] + 1));  // +1 self-loop
        }
    }
    if (b == nb - 1 && t == 0) off_g[n] = end;
    for (int i = base + t; i < end; i += 256) {
        uint32_t r = ebuf[i];
        int slot = atomicAdd(&cur[(r >> 17) & (NPB - 1)], 1);
        csr[slot] = (int)(r & 0x1FFFF);
    }
}

// ---- g1 = (x @ W1) * dinv, packed f16x2 (16 words/node) ----
__launch_bounds__(256)
__global__ void k_mm1(const float* __restrict__ x, const float* __restrict__ W1,
                      const float* __restrict__ dinv, uint32_t* __restrict__ g1, int n) {
    __shared__ float Ws[F_IN * F_HID];
    __shared__ float xs[8 * F_IN];
    int t = threadIdx.x;
    ((float4*)Ws)[t] = ((const float4*)W1)[t];  // 1024 floats = 256 float4
    int nl = t >> 5, c = t & 31;
    int node = blockIdx.x * 8 + nl;
    if (node < n) xs[t] = x[(size_t)node * F_IN + c];
    __syncthreads();
    if (node >= n) return;
    float sum = 0.f;
    #pragma unroll
    for (int k = 0; k < F_IN; ++k) sum += xs[nl * F_IN + k] * Ws[k * F_HID + c];
    float gv = sum * dinv[node];
    float hi = __shfl_xor(gv, 1);
    if ((c & 1) == 0) {
        union { __half2 h; uint32_t u; } pk;
        pk.h = __floats2half2_rn(gv, hi);
        g1[(size_t)node * 16 + (c >> 1)] = pk.u;
    }
}

// ---- agg1: 2 nodes/wave, 8 edge slots x 4 lanes x 16B; pk_add accumulate ----
__launch_bounds__(256)
__global__ void k_agg1(const uint32_t* __restrict__ g1, const int* __restrict__ csr,
                       const int* __restrict__ off_g,
                       const float* __restrict__ dinv, const float* __restrict__ b1,
                       uint32_t* __restrict__ h, int n) {
    int t = threadIdx.x, wv = t >> 6, lane = t & 63;
    int half = lane >> 5, l = lane & 31;
    int v = blockIdx.x * 8 + wv * 2 + half;
    if (v >= n) return;
    int q = l & 3, slot = l >> 2;  // 8 edge slots, 4 lanes x 16B per row
    int start = off_g[v], cnt = off_g[v + 1] - start;
    uint4 acc;
    if (slot == 0) acc = *(const uint4*)(g1 + (size_t)v * 16 + q * 4);  // self-loop
    else acc = make_uint4(0u, 0u, 0u, 0u);
    for (int k = slot; k < cnt; k += 8) {
        int s = csr[start + k];
        uint4 w = *(const uint4*)(g1 + (size_t)s * 16 + q * 4);
        acc.x = pk_add(acc.x, w.x);
        acc.y = pk_add(acc.y, w.y);
        acc.z = pk_add(acc.z, w.z);
        acc.w = pk_add(acc.w, w.w);
    }
    #pragma unroll
    for (int off = 4; off < 32; off <<= 1) {
        acc.x = pk_add(acc.x, (uint32_t)__shfl_xor((int)acc.x, off));
        acc.y = pk_add(acc.y, (uint32_t)__shfl_xor((int)acc.y, off));
        acc.z = pk_add(acc.z, (uint32_t)__shfl_xor((int)acc.z, off));
        acc.w = pk_add(acc.w, (uint32_t)__shfl_xor((int)acc.w, off));
    }
    if (slot == 0) {
        float di = dinv[v];
        float4 bA = *(const float4*)(b1 + 8 * q);
        float4 bB = *(const float4*)(b1 + 8 * q + 4);
        union { uint32_t u; __half2 h; } w0, w1, w2, w3;
        w0.u = acc.x; w1.u = acc.y; w2.u = acc.z; w3.u = acc.w;
        float2 f0 = __half22float2(w0.h), f1 = __half22float2(w1.h);
        float2 f2 = __half22float2(w2.h), f3 = __half22float2(w3.h);
        float h0 = ftanh(f0.x * di + bA.x), h1 = ftanh(f0.y * di + bA.y);
        float h2 = ftanh(f1.x * di + bA.z), h3 = ftanh(f1.y * di + bA.w);
        float h4 = ftanh(f2.x * di + bB.x), h5 = ftanh(f2.y * di + bB.y);
        float h6 = ftanh(f3.x * di + bB.z), h7 = ftanh(f3.y * di + bB.w);
        union { __half2 h; uint32_t u; } o0, o1, o2, o3;
        o0.h = __floats2half2_rn(h0, h1);
        o1.h = __floats2half2_rn(h2, h3);
        o2.h = __floats2half2_rn(h4, h5);
        o3.h = __floats2half2_rn(h6, h7);
        *(uint4*)(h + (size_t)v * 16 + q * 4) = make_uint4(o0.u, o1.u, o2.u, o3.u);
    }
}

// ---- g2 = (h @ W2) * dinv, packed f16x2 (8 words/node) ----
__launch_bounds__(256)
__global__ void k_mm2(const uint32_t* __restrict__ h, const float* __restrict__ W2,
                      const float* __restrict__ dinv, uint32_t* __restrict__ g2, int n) {
    __shared__ float Ws[F_HID * F_OUT];
    __shared__ float hs[16 * F_HID];
    int t = threadIdx.x;
    if (t < 128) ((float4*)Ws)[t] = ((const float4*)W2)[t];  // 512 floats
    int node0 = blockIdx.x * 16;
    {
        int nl = t >> 4, cp = t & 15;
        int node = node0 + nl;
        float a = 0.f, bb = 0.f;
        if (node < n) {
            union { uint32_t u; __half2 h; } p;
            p.u = h[(size_t)node * 16 + cp];
            float2 f = __half22float2(p.h);
            a = f.x; bb = f.y;
        }
        hs[nl * F_HID + 2 * cp]     = a;
        hs[nl * F_HID + 2 * cp + 1] = bb;
    }
    __syncthreads();
    int nl = t >> 4, c = t & 15;
    int node = node0 + nl;
    if (node >= n) return;
    float s = 0.f;
    #pragma unroll
    for (int k = 0; k < F_HID; ++k) s += hs[nl * F_HID + k] * Ws[k * F_OUT + c];
    float gv = s * dinv[node];
    float hi = __shfl_xor(gv, 1);
    if ((c & 1) == 0) {
        union { __half2 h; uint32_t u; } pk;
        pk.h = __floats2half2_rn(gv, hi);
        g2[(size_t)node * 8 + (c >> 1)] = pk.u;
    }
}

// ---- agg2: 2 nodes/wave, 8 slots x 4 lanes x 8B; fused log_softmax ----
__launch_bounds__(256)
__global__ void k_agg2(const uint32_t* __restrict__ g2, const int* __restrict__ csr,
                       const int* __restrict__ off_g,
                       const float* __restrict__ dinv, const float* __restrict__ b2,
                       float* __restrict__ out_h, float* __restrict__ out_ls, int n) {
    int t = threadIdx.x, wv = t >> 6, lane = t & 63;
    int half = lane >> 5, l = lane & 31;
    int v = blockIdx.x * 8 + wv * 2 + half;
    if (v >= n) return;
    int q = l & 3, slot = l >> 2;  // 8 slots, 4 lanes x 8B per 32B row
    int start = off_g[v], cnt = off_g[v + 1] - start;
    uint2 acc;
    if (slot == 0) acc = *(const uint2*)(g2 + (size_t)v * 8 + q * 2);  // self-loop
    else acc = make_uint2(0u, 0u);
    for (int k = slot; k < cnt; k += 8) {
        int s = csr[start + k];
        uint2 w = *(const uint2*)(g2 + (size_t)s * 8 + q * 2);
        acc.x = pk_add(acc.x, w.x);
        acc.y = pk_add(acc.y, w.y);
    }
    #pragma unroll
    for (int off = 4; off < 32; off <<= 1) {
        acc.x = pk_add(acc.x, (uint32_t)__shfl_xor((int)acc.x, off));
        acc.y = pk_add(acc.y, (uint32_t)__shfl_xor((int)acc.y, off));
    }
    if (slot == 0) {
        float di = dinv[v];
        float4 bb = *(const float4*)(b2 + 4 * q);
        union { uint32_t u; __half2 h; } w0, w1;
        w0.u = acc.x; w1.u = acc.y;
        float2 f0 = __half22float2(w0.h), f1 = __half22float2(w1.h);
        float val0 = f0.x * di + bb.x, val1 = f0.y * di + bb.y;
        float val2 = f1.x * di + bb.z, val3 = f1.y * di + bb.w;
        float m = fmaxf(fmaxf(val0, val1), fmaxf(val2, val3));
        m = fmaxf(m, __shfl_xor(m, 1));
        m = fmaxf(m, __shfl_xor(m, 2));
        float S = fexp(val0 - m) + fexp(val1 - m) + fexp(val2 - m) + fexp(val3 - m);
        S += __shfl_xor(S, 1);
        S += __shfl_xor(S, 2);
        float L = __builtin_amdgcn_logf(S) * 0.69314718056f + m;
        *(float4*)(out_h + (size_t)v * F_OUT + 4 * q) =
            make_float4(val0, val1, val2, val3);
        *(float4*)(out_ls + (size_t)v * F_OUT + 4 * q) =
            make_float4(val0 - L, val1 - L, val2 - L, val3 - L);
    }
}

extern "C" void kernel_launch(void* const* d_in, const int* in_sizes, int n_in,
                              void* d_out, int out_size, void* d_ws, size_t ws_size,
                              hipStream_t stream) {
    const float* x  = (const float*)d_in[0];
    const int*   ei = (const int*)d_in[1];   // [2,E]: [0:E]=src, [E:2E]=dst
    const float* W1 = (const float*)d_in[2];
    const float* b1 = (const float*)d_in[3];
    const float* W2 = (const float*)d_in[4];
    const float* b2 = (const float*)d_in[5];

    int n  = in_sizes[0] / F_IN;
    int ne = in_sizes[1] / 2;
    int nb = (n + NPB - 1) / NPB;
    int chunk = (ne + BH - 1) / BH;

    float* out_h  = (float*)d_out;
    float* out_ls = out_h + (size_t)n * F_OUT;

    char* p = (char*)d_ws;
    float*    dinv     = (float*)p;    p += (size_t)n * sizeof(float);
    int*      totalG   = (int*)p;      p += MAXNB * sizeof(int);
    int*      boff     = (int*)p;      p += (MAXNB + 4) * sizeof(int);
    int*      off_g    = (int*)p;      p += ((size_t)n + 4) * sizeof(int);
    int*      hist_mat = (int*)p;      p += (size_t)BH * nb * sizeof(int);
    int*      off_mat  = (int*)p;      p += (size_t)BH * nb * sizeof(int);
    uint32_t* ebuf     = (uint32_t*)p; p += (size_t)ne * sizeof(uint32_t);
    int*      csr      = (int*)p;      p += (size_t)ne * sizeof(int);
    uint32_t* g1       = (uint32_t*)p; p += (size_t)n * 16 * sizeof(uint32_t);
    uint32_t* h        = (uint32_t*)p; p += (size_t)n * 16 * sizeof(uint32_t);
    uint32_t* g2       = (uint32_t*)p; p += (size_t)n * 8 * sizeof(uint32_t);

    k_init   <<<(MAXNB + 255) / 256, 256, 0, stream>>>(totalG);
    k_hist   <<<BH, 1024, 0, stream>>>(ei, ne, chunk, nb, hist_mat, totalG);
    k_scanb  <<<1, 256, 0, stream>>>(totalG, boff, nb);
    k_colscan<<<(nb + 255) / 256, 256, 0, stream>>>(boff, hist_mat, off_mat, nb);
    k_fillc  <<<BH, 1024, 0, stream>>>(ei, ne, chunk, nb, off_mat, ebuf);
    k_pass2  <<<nb, 256, 0, stream>>>(ebuf, boff, csr, off_g, dinv, n, nb);

    k_mm1    <<<(n + 7) / 8, 256, 0, stream>>>(x, W1, dinv, g1, n);
    k_agg1   <<<(n + 7) / 8, 256, 0, stream>>>(g1, csr, off_g, dinv, b1, h, n);
    k_mm2    <<<(n + 15) / 16, 256, 0, stream>>>(h, W2, dinv, g2, n);
    k_agg2   <<<(n + 7) / 8, 256, 0, stream>>>(g2, csr, off_g, dinv, b2, out_h, out_ls, n);
}

// Round 9
// 124.431 us; speedup vs baseline: 8.1012x; 1.1097x over previous
//
#include <hip/hip_runtime.h>
#include <hip/hip_bf16.h>
#include <hip/hip_fp16.h>
#include <math.h>
#include <stdint.h>

#define F_IN  32
#define F_HID 32
#define F_OUT 16
#define NPB     64     // nodes per bucket
#define LOG_NPB 6
#define MAXNB   2048   // supports n <= 131072
#define BH      256    // histogram/fill blocks

__device__ inline uint32_t pk_add(uint32_t a, uint32_t b) {
    union { uint32_t u; __half2 h; } x, y, r;
    x.u = a; y.u = b;
    r.h = __hadd2(x.h, y.h);
    return r.u;
}

__device__ inline float fexp(float x) {           // e^x
    return __builtin_amdgcn_exp2f(x * 1.44269504089f);
}
__device__ inline float ftanh(float x) {          // tanh via exp2+rcp
    x = fminf(fmaxf(x, -15.f), 15.f);
    float t = __builtin_amdgcn_exp2f(x * 2.88539008178f);  // e^(2x)
    return (t - 1.0f) * __builtin_amdgcn_rcpf(t + 1.0f);
}

// ---- pass A: per-block bucket histogram (no global atomics) ----
__launch_bounds__(1024)
__global__ void k_hist(const int* __restrict__ ei, int ne, int chunk, int nb,
                       int* __restrict__ hist_mat) {
    __shared__ int hist[MAXNB];
    int t = threadIdx.x, b = blockIdx.x;
    for (int i = t; i < nb; i += 1024) hist[i] = 0;
    __syncthreads();
    long s = (long)b * chunk;
    long e = s + chunk; if (e > ne) e = ne;
    for (long i = s + t; i < e; i += 1024)
        atomicAdd(&hist[ei[ne + i] >> LOG_NPB], 1);
    __syncthreads();
    for (int i = t; i < nb; i += 1024)
        hist_mat[(size_t)b * nb + i] = hist[i];
}

// ---- column scan: off_mat[b][k] = local exclusive prefix; totalG[k] = column sum ----
__global__ void k_colscan(const int* __restrict__ hist_mat, int* __restrict__ off_mat,
                          int* __restrict__ totalG, int nb) {
    int k = blockIdx.x * 256 + threadIdx.x;
    if (k >= nb) return;
    int run = 0;
    #pragma unroll 8
    for (int b = 0; b < BH; ++b) {
        size_t idx = (size_t)b * nb + k;
        int h = hist_mat[idx];
        off_mat[idx] = run;
        run += h;
    }
    totalG[k] = run;
}

// ---- exclusive scan of totalG -> boff[0..nb] (single block) ----
__global__ void k_scanb(const int* __restrict__ totalG, int* __restrict__ boff, int nb) {
    __shared__ int sh[256];
    int t = threadIdx.x;
    int base = t * 8;
    int v[8], s = 0;
    #pragma unroll
    for (int j = 0; j < 8; ++j) {
        v[j] = (base + j < nb) ? totalG[base + j] : 0;
        s += v[j];
    }
    sh[t] = s; __syncthreads();
    for (int o = 1; o < 256; o <<= 1) {
        int u = (t >= o) ? sh[t - o] : 0;
        __syncthreads();
        sh[t] += u;
        __syncthreads();
    }
    int run = sh[t] - s;  // exclusive prefix
    #pragma unroll
    for (int j = 0; j < 8; ++j) {
        int k = base + j;
        if (k < nb) { boff[k] = run; run += v[j]; }
    }
    if (t == 255) boff[nb] = sh[255];
}

// ---- pass C: place edges into bucket-grouped ebuf via LDS cursors ----
__launch_bounds__(1024)
__global__ void k_fillc(const int* __restrict__ ei, int ne, int chunk, int nb,
                        const int* __restrict__ off_mat, const int* __restrict__ boff,
                        uint32_t* __restrict__ ebuf) {
    __shared__ int cur[MAXNB];
    int t = threadIdx.x, b = blockIdx.x;
    for (int i = t; i < nb; i += 1024)
        cur[i] = off_mat[(size_t)b * nb + i] + boff[i];
    __syncthreads();
    long s = (long)b * chunk;
    long e = s + chunk; if (e > ne) e = ne;
    for (long i = s + t; i < e; i += 1024) {
        int sn = ei[i], dn = ei[ne + i];
        int slot = atomicAdd(&cur[dn >> LOG_NPB], 1);
        ebuf[slot] = (uint32_t)sn | ((uint32_t)(dn & (NPB - 1)) << 17);
    }
}

// ---- pass 2: within-bucket sort -> csr + off_g (n+1 entries) + dinv ----
__launch_bounds__(256)
__global__ void k_pass2(const uint32_t* __restrict__ ebuf, const int* __restrict__ boff,
                        int* __restrict__ csr, int* __restrict__ off_g,
                        float* __restrict__ dinv, int n, int nb) {
    __shared__ int hist[NPB], scn[NPB], cur[NPB];
    int b = blockIdx.x, t = threadIdx.x;
    int base = boff[b], end = boff[b + 1];
    if (t < NPB) hist[t] = 0;
    __syncthreads();
    for (int i = base + t; i < end; i += 256)
        atomicAdd(&hist[(ebuf[i] >> 17) & (NPB - 1)], 1);
    __syncthreads();
    if (t == 0) {
        int run = base;
        for (int l = 0; l < NPB; ++l) { scn[l] = run; cur[l] = run; run += hist[l]; }
    }
    __syncthreads();
    if (t < NPB) {
        int v = (b << LOG_NPB) + t;
        if (v < n) {
            off_g[v] = scn[t];
            dinv[v] = rsqrtf((float)(hist[t] + 1));  // +1 self-loop
        }
    }
    if (b == nb - 1 && t == 0) off_g[n] = end;
    for (int i = base + t; i < end; i += 256) {
        uint32_t r = ebuf[i];
        int slot = atomicAdd(&cur[(r >> 17) & (NPB - 1)], 1);
        csr[slot] = (int)(r & 0x1FFFF);
    }
}

// ---- g1 = (x @ W1) * dinv, packed f16x2 (16 words/node) ----
__launch_bounds__(256)
__global__ void k_mm1(const float* __restrict__ x, const float* __restrict__ W1,
                      const float* __restrict__ dinv, uint32_t* __restrict__ g1, int n) {
    __shared__ float Ws[F_IN * F_HID];
    __shared__ float xs[8 * F_IN];
    int t = threadIdx.x;
    ((float4*)Ws)[t] = ((const float4*)W1)[t];  // 1024 floats = 256 float4
    int nl = t >> 5, c = t & 31;
    int node = blockIdx.x * 8 + nl;
    if (node < n) xs[t] = x[(size_t)node * F_IN + c];
    __syncthreads();
    if (node >= n) return;
    float sum = 0.f;
    #pragma unroll
    for (int k = 0; k < F_IN; ++k) sum += xs[nl * F_IN + k] * Ws[k * F_HID + c];
    float gv = sum * dinv[node];
    float hi = __shfl_xor(gv, 1);
    if ((c & 1) == 0) {
        union { __half2 h; uint32_t u; } pk;
        pk.h = __floats2half2_rn(gv, hi);
        g1[(size_t)node * 16 + (c >> 1)] = pk.u;
    }
}

// ---- agg1 (+fused mm2): 2 nodes/wave gather; all-lane tanh; in-block h@W2 ----
__launch_bounds__(256)
__global__ void k_agg1(const uint32_t* __restrict__ g1, const int* __restrict__ csr,
                       const int* __restrict__ off_g,
                       const float* __restrict__ dinv, const float* __restrict__ b1,
                       const float* __restrict__ W2, uint32_t* __restrict__ g2, int n) {
    __shared__ float W2s[F_HID * F_OUT];
    __shared__ float hb[8][F_HID + 1];  // padded stride 33
    int t = threadIdx.x, wv = t >> 6, lane = t & 63;
    if (t < 128) ((float4*)W2s)[t] = ((const float4*)W2)[t];  // 512 floats
    int half = lane >> 5, l = lane & 31;
    int v = blockIdx.x * 8 + wv * 2 + half;
    bool act = v < n;
    int q = l & 3, slot = l >> 2;  // 8 edge slots x 4 lanes x 16B per 64B row
    uint4 acc = make_uint4(0u, 0u, 0u, 0u);
    if (act) {
        if (slot == 0) acc = *(const uint4*)(g1 + (size_t)v * 16 + q * 4);  // self
        int start = off_g[v], cnt = off_g[v + 1] - start;
        for (int k = slot; k < cnt; k += 8) {
            int s = csr[start + k];
            uint4 w = *(const uint4*)(g1 + (size_t)s * 16 + q * 4);
            acc.x = pk_add(acc.x, w.x);
            acc.y = pk_add(acc.y, w.y);
            acc.z = pk_add(acc.z, w.z);
            acc.w = pk_add(acc.w, w.w);
        }
    }
    #pragma unroll
    for (int off = 4; off < 32; off <<= 1) {   // butterfly: every lane gets q-sum
        acc.x = pk_add(acc.x, (uint32_t)__shfl_xor((int)acc.x, off));
        acc.y = pk_add(acc.y, (uint32_t)__shfl_xor((int)acc.y, off));
        acc.z = pk_add(acc.z, (uint32_t)__shfl_xor((int)acc.z, off));
        acc.w = pk_add(acc.w, (uint32_t)__shfl_xor((int)acc.w, off));
    }
    // redistribute: lane l takes channel ch=l of its half's node
    int ch = l;
    int src = (lane & 32) + (ch >> 3);  // lane with q == ch>>3
    uint32_t a0 = (uint32_t)__shfl((int)acc.x, src);
    uint32_t a1 = (uint32_t)__shfl((int)acc.y, src);
    uint32_t a2 = (uint32_t)__shfl((int)acc.z, src);
    uint32_t a3 = (uint32_t)__shfl((int)acc.w, src);
    int widx = (ch & 7) >> 1;
    uint32_t w = (widx & 2) ? ((widx & 1) ? a3 : a2) : ((widx & 1) ? a1 : a0);
    union { uint32_t u; __half2 h; } pw; pw.u = w;
    float2 f2 = __half22float2(pw.h);
    float f = (ch & 1) ? f2.y : f2.x;
    float di = act ? dinv[v] : 0.f;
    hb[wv * 2 + half][ch] = ftanh(f * di + b1[ch]);
    __syncthreads();
    // fused mm2: g2 = (h @ W2) * dinv, packed f16x2 (8 words/node)
    if (t < 128) {
        int node_l = t >> 4, c = t & 15;
        int v2 = blockIdx.x * 8 + node_l;
        float s = 0.f;
        #pragma unroll
        for (int k = 0; k < F_HID; ++k) s += hb[node_l][k] * W2s[k * F_OUT + c];
        float gv = (v2 < n) ? s * dinv[v2] : 0.f;
        float hi2 = __shfl_xor(gv, 1);
        if ((c & 1) == 0 && v2 < n) {
            union { __half2 h; uint32_t u; } pk2;
            pk2.h = __floats2half2_rn(gv, hi2);
            g2[(size_t)v2 * 8 + (c >> 1)] = pk2.u;
        }
    }
}

// ---- agg2: 2 nodes/wave gather; all-lane epilogue + fused log_softmax ----
__launch_bounds__(256)
__global__ void k_agg2(const uint32_t* __restrict__ g2, const int* __restrict__ csr,
                       const int* __restrict__ off_g,
                       const float* __restrict__ dinv, const float* __restrict__ b2,
                       float* __restrict__ out_h, float* __restrict__ out_ls, int n) {
    int t = threadIdx.x, wv = t >> 6, lane = t & 63;
    int half = lane >> 5, l = lane & 31;
    int v = blockIdx.x * 8 + wv * 2 + half;
    bool act = v < n;
    int q = l & 3, slot = l >> 2;  // 8 slots x 4 lanes x 8B per 32B row
    uint2 acc = make_uint2(0u, 0u);
    if (act) {
        if (slot == 0) acc = *(const uint2*)(g2 + (size_t)v * 8 + q * 2);  // self
        int start = off_g[v], cnt = off_g[v + 1] - start;
        for (int k = slot; k < cnt; k += 8) {
            int s = csr[start + k];
            uint2 w = *(const uint2*)(g2 + (size_t)s * 8 + q * 2);
            acc.x = pk_add(acc.x, w.x);
            acc.y = pk_add(acc.y, w.y);
        }
    }
    #pragma unroll
    for (int off = 4; off < 32; off <<= 1) {
        acc.x = pk_add(acc.x, (uint32_t)__shfl_xor((int)acc.x, off));
        acc.y = pk_add(acc.y, (uint32_t)__shfl_xor((int)acc.y, off));
    }
    if (l < 16) {
        int ch = l;
        int src = (lane & 32) + (ch >> 2);  // lane with q == ch>>2
        uint32_t a0 = (uint32_t)__shfl((int)acc.x, src);
        uint32_t a1 = (uint32_t)__shfl((int)acc.y, src);
        uint32_t w = (ch & 2) ? a1 : a0;
        union { uint32_t u; __half2 h; } pw; pw.u = w;
        float2 f2 = __half22float2(pw.h);
        float f = (ch & 1) ? f2.y : f2.x;
        float di = act ? dinv[v] : 0.f;
        float val = f * di + b2[ch];
        float m = val;
        m = fmaxf(m, __shfl_xor(m, 1));
        m = fmaxf(m, __shfl_xor(m, 2));
        m = fmaxf(m, __shfl_xor(m, 4));
        m = fmaxf(m, __shfl_xor(m, 8));
        float S = fexp(val - m);
        S += __shfl_xor(S, 1);
        S += __shfl_xor(S, 2);
        S += __shfl_xor(S, 4);
        S += __shfl_xor(S, 8);
        float L = __builtin_amdgcn_logf(S) * 0.69314718056f + m;
        if (act) {
            out_h[(size_t)v * F_OUT + ch]  = val;
            out_ls[(size_t)v * F_OUT + ch] = val - L;
        }
    }
}

extern "C" void kernel_launch(void* const* d_in, const int* in_sizes, int n_in,
                              void* d_out, int out_size, void* d_ws, size_t ws_size,
                              hipStream_t stream) {
    const float* x  = (const float*)d_in[0];
    const int*   ei = (const int*)d_in[1];   // [2,E]: [0:E]=src, [E:2E]=dst
    const float* W1 = (const float*)d_in[2];
    const float* b1 = (const float*)d_in[3];
    const float* W2 = (const float*)d_in[4];
    const float* b2 = (const float*)d_in[5];

    int n  = in_sizes[0] / F_IN;
    int ne = in_sizes[1] / 2;
    int nb = (n + NPB - 1) / NPB;
    int chunk = (ne + BH - 1) / BH;

    float* out_h  = (float*)d_out;
    float* out_ls = out_h + (size_t)n * F_OUT;

    char* p = (char*)d_ws;
    float*    dinv     = (float*)p;    p += (size_t)n * sizeof(float);
    int*      totalG   = (int*)p;      p += MAXNB * sizeof(int);
    int*      boff     = (int*)p;      p += (MAXNB + 4) * sizeof(int);
    int*      off_g    = (int*)p;      p += ((size_t)n + 4) * sizeof(int);
    int*      hist_mat = (int*)p;      p += (size_t)BH * nb * sizeof(int);
    int*      off_mat  = (int*)p;      p += (size_t)BH * nb * sizeof(int);
    uint32_t* ebuf     = (uint32_t*)p; p += (size_t)ne * sizeof(uint32_t);
    int*      csr      = (int*)p;      p += (size_t)ne * sizeof(int);
    uint32_t* g1       = (uint32_t*)p; p += (size_t)n * 16 * sizeof(uint32_t);
    uint32_t* g2       = (uint32_t*)p; p += (size_t)n * 8 * sizeof(uint32_t);

    k_hist   <<<BH, 1024, 0, stream>>>(ei, ne, chunk, nb, hist_mat);
    k_colscan<<<(nb + 255) / 256, 256, 0, stream>>>(hist_mat, off_mat, totalG, nb);
    k_scanb  <<<1, 256, 0, stream>>>(totalG, boff, nb);
    k_fillc  <<<BH, 1024, 0, stream>>>(ei, ne, chunk, nb, off_mat, boff, ebuf);
    k_pass2  <<<nb, 256, 0, stream>>>(ebuf, boff, csr, off_g, dinv, n, nb);

    k_mm1    <<<(n + 7) / 8, 256, 0, stream>>>(x, W1, dinv, g1, n);
    k_agg1   <<<(n + 7) / 8, 256, 0, stream>>>(g1, csr, off_g, dinv, b1, W2, g2, n);
    k_agg2   <<<(n + 7) / 8, 256, 0, stream>>>(g2, csr, off_g, dinv, b2, out_h, out_ls, n);
}

// Round 10
// 119.591 us; speedup vs baseline: 8.4290x; 1.0405x over previous
//
#include <hip/hip_runtime.h>
#include <hip/hip_bf16.h>
#include <hip/hip_fp16.h>
#include <math.h>
#include <stdint.h>

#define F_IN  32
#define F_HID 32
#define F_OUT 16
#define NPB     256    // nodes per bucket
#define LOG_NPB 8
#define MAXNB   512    // supports n <= 131072
#define BH      256    // histogram/fill blocks

__device__ inline uint32_t pk_add(uint32_t a, uint32_t b) {
    union { uint32_t u; __half2 h; } x, y, r;
    x.u = a; y.u = b;
    r.h = __hadd2(x.h, y.h);
    return r.u;
}

__device__ inline float fexp(float x) {           // e^x
    return __builtin_amdgcn_exp2f(x * 1.44269504089f);
}
__device__ inline float ftanh(float x) {          // tanh via exp2+rcp
    x = fminf(fmaxf(x, -15.f), 15.f);
    float t = __builtin_amdgcn_exp2f(x * 2.88539008178f);  // e^(2x)
    return (t - 1.0f) * __builtin_amdgcn_rcpf(t + 1.0f);
}

// ---- pass A: per-block bucket histogram (vectorized dst reads) ----
__launch_bounds__(1024)
__global__ void k_hist(const int* __restrict__ ei, int ne, int chunk, int nb,
                       int* __restrict__ hist_mat) {
    __shared__ int hist[MAXNB];
    int t = threadIdx.x, b = blockIdx.x;
    for (int i = t; i < nb; i += 1024) hist[i] = 0;
    __syncthreads();
    long s = (long)b * chunk;
    long e = s + chunk; if (e > ne) e = ne;
    const int* dstp = ei + ne;
    long i = s + (long)t * 4;
    for (; i + 4 <= e; i += 4096) {
        int4 d = *(const int4*)(dstp + i);
        atomicAdd(&hist[d.x >> LOG_NPB], 1);
        atomicAdd(&hist[d.y >> LOG_NPB], 1);
        atomicAdd(&hist[d.z >> LOG_NPB], 1);
        atomicAdd(&hist[d.w >> LOG_NPB], 1);
    }
    if (i < e)
        for (long j = i; j < e; ++j) atomicAdd(&hist[dstp[j] >> LOG_NPB], 1);
    __syncthreads();
    for (int k = t; k < nb; k += 1024)
        hist_mat[(size_t)b * nb + k] = hist[k];
}

// ---- column scan: off_mat[b][k] = per-block exclusive prefix; totalG[k] = col sum ----
__global__ void k_colscan(const int* __restrict__ hist_mat, int* __restrict__ off_mat,
                          int* __restrict__ totalG, int nb) {
    int k = blockIdx.x * 256 + threadIdx.x;
    if (k >= nb) return;
    int run = 0;
    #pragma unroll 8
    for (int b = 0; b < BH; ++b) {
        size_t idx = (size_t)b * nb + k;
        int h = hist_mat[idx];
        off_mat[idx] = run;
        run += h;
    }
    totalG[k] = run;
}

// ---- exclusive scan of totalG -> boff[0..nb] (single block) ----
__global__ void k_scanb(const int* __restrict__ totalG, int* __restrict__ boff, int nb) {
    __shared__ int sh[256];
    int t = threadIdx.x;
    int base = t * 2;
    int v[2], s = 0;
    #pragma unroll
    for (int j = 0; j < 2; ++j) {
        v[j] = (base + j < nb) ? totalG[base + j] : 0;
        s += v[j];
    }
    sh[t] = s; __syncthreads();
    for (int o = 1; o < 256; o <<= 1) {
        int u = (t >= o) ? sh[t - o] : 0;
        __syncthreads();
        sh[t] += u;
        __syncthreads();
    }
    int run = sh[t] - s;  // exclusive prefix
    #pragma unroll
    for (int j = 0; j < 2; ++j) {
        int k = base + j;
        if (k < nb) { boff[k] = run; run += v[j]; }
    }
    if (t == 255) boff[nb] = sh[255];
}

// ---- pass C: place edges into bucket-grouped ebuf via LDS cursors ----
__launch_bounds__(1024)
__global__ void k_fillc(const int* __restrict__ ei, int ne, int chunk, int nb,
                        const int* __restrict__ off_mat, const int* __restrict__ boff,
                        uint32_t* __restrict__ ebuf) {
    __shared__ int cur[MAXNB];
    int t = threadIdx.x, b = blockIdx.x;
    for (int i = t; i < nb; i += 1024)
        cur[i] = off_mat[(size_t)b * nb + i] + boff[i];
    __syncthreads();
    long s = (long)b * chunk;
    long e = s + chunk; if (e > ne) e = ne;
    const int* srcp = ei;
    const int* dstp = ei + ne;
    long i = s + (long)t * 4;
    for (; i + 4 <= e; i += 4096) {
        int4 sv = *(const int4*)(srcp + i);
        int4 dv = *(const int4*)(dstp + i);
        int p0 = atomicAdd(&cur[dv.x >> LOG_NPB], 1);
        ebuf[p0] = (uint32_t)sv.x | ((uint32_t)(dv.x & (NPB - 1)) << 17);
        int p1 = atomicAdd(&cur[dv.y >> LOG_NPB], 1);
        ebuf[p1] = (uint32_t)sv.y | ((uint32_t)(dv.y & (NPB - 1)) << 17);
        int p2 = atomicAdd(&cur[dv.z >> LOG_NPB], 1);
        ebuf[p2] = (uint32_t)sv.z | ((uint32_t)(dv.z & (NPB - 1)) << 17);
        int p3 = atomicAdd(&cur[dv.w >> LOG_NPB], 1);
        ebuf[p3] = (uint32_t)sv.w | ((uint32_t)(dv.w & (NPB - 1)) << 17);
    }
    if (i < e) {
        for (long j = i; j < e; ++j) {
            int sn = srcp[j], dn = dstp[j];
            int p = atomicAdd(&cur[dn >> LOG_NPB], 1);
            ebuf[p] = (uint32_t)sn | ((uint32_t)(dn & (NPB - 1)) << 17);
        }
    }
}

// ---- pass 2: within-bucket sort -> csr + off_g + dinv + xd = x*dinv (f16x2) ----
__launch_bounds__(256)
__global__ void k_pass2(const uint32_t* __restrict__ ebuf, const int* __restrict__ boff,
                        const float* __restrict__ x,
                        int* __restrict__ csr, int* __restrict__ off_g,
                        float* __restrict__ dinv, uint32_t* __restrict__ xd,
                        int n, int nb) {
    __shared__ int hist[NPB], scn[NPB], cur[NPB];
    __shared__ float sdi[NPB];
    int b = blockIdx.x, t = threadIdx.x;
    int base = boff[b], end = boff[b + 1];
    int v0 = b << LOG_NPB;
    hist[t] = 0;
    __syncthreads();
    for (int i = base + t; i < end; i += 256)
        atomicAdd(&hist[(ebuf[i] >> 17) & (NPB - 1)], 1);
    __syncthreads();
    int val = hist[t];
    scn[t] = val; __syncthreads();
    for (int o = 1; o < 256; o <<= 1) {
        int u = (t >= o) ? scn[t - o] : 0;
        __syncthreads();
        scn[t] += u;
        __syncthreads();
    }
    int excl = scn[t] - val + base;
    cur[t] = excl;
    int v = v0 + t;
    float d = 0.f;
    if (v < n) {
        off_g[v] = excl;
        d = rsqrtf((float)(val + 1));  // +1 self-loop
        dinv[v] = d;
    }
    sdi[t] = d;
    if (b == nb - 1 && t == 0) off_g[n] = end;
    __syncthreads();
    for (int i = base + t; i < end; i += 256) {
        uint32_t r = ebuf[i];
        int slot = atomicAdd(&cur[(r >> 17) & (NPB - 1)], 1);
        csr[slot] = (int)(r & 0x1FFFF);
    }
    // xd = x * dinv, packed f16x2 (16 words/node)
    for (int i = t; i < NPB * 16; i += 256) {
        int nl = i >> 4, wp = i & 15;
        int vv = v0 + nl;
        if (vv < n) {
            float2 xx = *(const float2*)(x + (size_t)vv * F_IN + 2 * wp);
            float di = sdi[nl];
            union { __half2 h; uint32_t u; } pk;
            pk.h = __floats2half2_rn(xx.x * di, xx.y * di);
            xd[(size_t)vv * 16 + wp] = pk.u;
        }
    }
}

// ---- agg1: gather xd, reduce, then (sum@W1 -> tanh -> @W2)*dinv -> g2 ----
__launch_bounds__(256)
__global__ void k_agg1(const uint32_t* __restrict__ xd, const int* __restrict__ csr,
                       const int* __restrict__ off_g,
                       const float* __restrict__ dinv, const float* __restrict__ b1,
                       const float* __restrict__ W1, const float* __restrict__ W2,
                       uint32_t* __restrict__ g2, int n) {
    __shared__ float W1s[F_IN * F_HID];
    __shared__ float W2s[F_HID * F_OUT];
    __shared__ float sums[8][F_IN + 1];
    __shared__ float hb[8][F_HID + 1];
    int t = threadIdx.x, wv = t >> 6, lane = t & 63;
    ((float4*)W1s)[t] = ((const float4*)W1)[t];            // 1024 floats
    if (t < 128) ((float4*)W2s)[t] = ((const float4*)W2)[t];  // 512 floats
    int half = lane >> 5, l = lane & 31;
    int v = blockIdx.x * 8 + wv * 2 + half;
    bool act = v < n;
    int q = l & 3, slot = l >> 2;  // 8 edge slots x 4 lanes x 16B per 64B row
    uint4 acc = make_uint4(0u, 0u, 0u, 0u);
    if (act) {
        acc = (slot == 0) ? *(const uint4*)(xd + (size_t)v * 16 + q * 4)  // self
                          : make_uint4(0u, 0u, 0u, 0u);
        int start = off_g[v], cnt = off_g[v + 1] - start;
        for (int k = slot; k < cnt; k += 8) {
            int s = csr[start + k];
            uint4 w = *(const uint4*)(xd + (size_t)s * 16 + q * 4);
            acc.x = pk_add(acc.x, w.x);
            acc.y = pk_add(acc.y, w.y);
            acc.z = pk_add(acc.z, w.z);
            acc.w = pk_add(acc.w, w.w);
        }
    }
    #pragma unroll
    for (int off = 4; off < 32; off <<= 1) {   // butterfly across slots
        acc.x = pk_add(acc.x, (uint32_t)__shfl_xor((int)acc.x, off));
        acc.y = pk_add(acc.y, (uint32_t)__shfl_xor((int)acc.y, off));
        acc.z = pk_add(acc.z, (uint32_t)__shfl_xor((int)acc.z, off));
        acc.w = pk_add(acc.w, (uint32_t)__shfl_xor((int)acc.w, off));
    }
    // redistribute: lane l takes channel ch=l of its half's node
    int ch = l;
    int src = (lane & 32) + (ch >> 3);  // lane with q == ch>>3
    uint32_t a0 = (uint32_t)__shfl((int)acc.x, src);
    uint32_t a1 = (uint32_t)__shfl((int)acc.y, src);
    uint32_t a2 = (uint32_t)__shfl((int)acc.z, src);
    uint32_t a3 = (uint32_t)__shfl((int)acc.w, src);
    int widx = (ch & 7) >> 1;
    uint32_t w = (widx & 2) ? ((widx & 1) ? a3 : a2) : ((widx & 1) ? a1 : a0);
    union { uint32_t u; __half2 h; } pw; pw.u = w;
    float2 f2 = __half22float2(pw.h);
    sums[wv * 2 + half][ch] = (ch & 1) ? f2.y : f2.x;
    __syncthreads();
    // matmul1 + tanh: 256 threads = 8 nodes x 32 ch
    {
        int nl = t >> 5, c = t & 31;
        int v1 = blockIdx.x * 8 + nl;
        float di = (v1 < n) ? dinv[v1] : 0.f;
        float s = 0.f;
        #pragma unroll
        for (int k = 0; k < F_IN; ++k) s += sums[nl][k] * W1s[k * F_HID + c];
        hb[nl][c] = ftanh(s * di + b1[c]);
    }
    __syncthreads();
    // matmul2: g2 = (h @ W2) * dinv, packed f16x2 (8 words/node)
    if (t < 128) {
        int nl = t >> 4, c = t & 15;
        int v2 = blockIdx.x * 8 + nl;
        float s = 0.f;
        #pragma unroll
        for (int k = 0; k < F_HID; ++k) s += hb[nl][k] * W2s[k * F_OUT + c];
        float gv = (v2 < n) ? s * dinv[v2] : 0.f;
        float hi2 = __shfl_xor(gv, 1);
        if ((c & 1) == 0 && v2 < n) {
            union { __half2 h; uint32_t u; } pk2;
            pk2.h = __floats2half2_rn(gv, hi2);
            g2[(size_t)v2 * 8 + (c >> 1)] = pk2.u;
        }
    }
}

// ---- agg2: 2 nodes/wave gather; all-lane epilogue + fused log_softmax ----
__launch_bounds__(256)
__global__ void k_agg2(const uint32_t* __restrict__ g2, const int* __restrict__ csr,
                       const int* __restrict__ off_g,
                       const float* __restrict__ dinv, const float* __restrict__ b2,
                       float* __restrict__ out_h, float* __restrict__ out_ls, int n) {
    int t = threadIdx.x, wv = t >> 6, lane = t & 63;
    int half = lane >> 5, l = lane & 31;
    int v = blockIdx.x * 8 + wv * 2 + half;
    bool act = v < n;
    int q = l & 3, slot = l >> 2;  // 8 slots x 4 lanes x 8B per 32B row
    uint2 acc = make_uint2(0u, 0u);
    if (act) {
        if (slot == 0) acc = *(const uint2*)(g2 + (size_t)v * 8 + q * 2);  // self
        int start = off_g[v], cnt = off_g[v + 1] - start;
        for (int k = slot; k < cnt; k += 8) {
            int s = csr[start + k];
            uint2 w = *(const uint2*)(g2 + (size_t)s * 8 + q * 2);
            acc.x = pk_add(acc.x, w.x);
            acc.y = pk_add(acc.y, w.y);
        }
    }
    #pragma unroll
    for (int off = 4; off < 32; off <<= 1) {
        acc.x = pk_add(acc.x, (uint32_t)__shfl_xor((int)acc.x, off));
        acc.y = pk_add(acc.y, (uint32_t)__shfl_xor((int)acc.y, off));
    }
    if (l < 16) {
        int ch = l;
        int src = (lane & 32) + (ch >> 2);  // lane with q == ch>>2
        uint32_t a0 = (uint32_t)__shfl((int)acc.x, src);
        uint32_t a1 = (uint32_t)__shfl((int)acc.y, src);
        uint32_t w = (ch & 2) ? a1 : a0;
        union { uint32_t u; __half2 h; } pw; pw.u = w;
        float2 f2 = __half22float2(pw.h);
        float f = (ch & 1) ? f2.y : f2.x;
        float di = act ? dinv[v] : 0.f;
        float val = f * di + b2[ch];
        float m = val;
        m = fmaxf(m, __shfl_xor(m, 1));
        m = fmaxf(m, __shfl_xor(m, 2));
        m = fmaxf(m, __shfl_xor(m, 4));
        m = fmaxf(m, __shfl_xor(m, 8));
        float S = fexp(val - m);
        S += __shfl_xor(S, 1);
        S += __shfl_xor(S, 2);
        S += __shfl_xor(S, 4);
        S += __shfl_xor(S, 8);
        float L = __builtin_amdgcn_logf(S) * 0.69314718056f + m;
        if (act) {
            out_h[(size_t)v * F_OUT + ch]  = val;
            out_ls[(size_t)v * F_OUT + ch] = val - L;
        }
    }
}

static inline size_t align16(size_t x) { return (x + 15) & ~(size_t)15; }

extern "C" void kernel_launch(void* const* d_in, const int* in_sizes, int n_in,
                              void* d_out, int out_size, void* d_ws, size_t ws_size,
                              hipStream_t stream) {
    const float* x  = (const float*)d_in[0];
    const int*   ei = (const int*)d_in[1];   // [2,E]: [0:E]=src, [E:2E]=dst
    const float* W1 = (const float*)d_in[2];
    const float* b1 = (const float*)d_in[3];
    const float* W2 = (const float*)d_in[4];
    const float* b2 = (const float*)d_in[5];

    int n  = in_sizes[0] / F_IN;
    int ne = in_sizes[1] / 2;
    int nb = (n + NPB - 1) / NPB;
    int chunk = (((ne + BH - 1) / BH) + 3) & ~3;  // multiple of 4 for int4 loads

    float* out_h  = (float*)d_out;
    float* out_ls = out_h + (size_t)n * F_OUT;

    char* p = (char*)d_ws;
    float*    dinv     = (float*)p;    p += align16((size_t)n * sizeof(float));
    int*      totalG   = (int*)p;      p += align16(MAXNB * sizeof(int));
    int*      boff     = (int*)p;      p += align16((MAXNB + 4) * sizeof(int));
    int*      off_g    = (int*)p;      p += align16(((size_t)n + 4) * sizeof(int));
    int*      hist_mat = (int*)p;      p += align16((size_t)BH * nb * sizeof(int));
    int*      off_mat  = (int*)p;      p += align16((size_t)BH * nb * sizeof(int));
    uint32_t* ebuf     = (uint32_t*)p; p += align16((size_t)ne * sizeof(uint32_t));
    int*      csr      = (int*)p;      p += align16((size_t)ne * sizeof(int));
    uint32_t* xd       = (uint32_t*)p; p += align16((size_t)n * 16 * sizeof(uint32_t));
    uint32_t* g2       = (uint32_t*)p; p += align16((size_t)n * 8 * sizeof(uint32_t));

    k_hist   <<<BH, 1024, 0, stream>>>(ei, ne, chunk, nb, hist_mat);
    k_colscan<<<(nb + 255) / 256, 256, 0, stream>>>(hist_mat, off_mat, totalG, nb);
    k_scanb  <<<1, 256, 0, stream>>>(totalG, boff, nb);
    k_fillc  <<<BH, 1024, 0, stream>>>(ei, ne, chunk, nb, off_mat, boff, ebuf);
    k_pass2  <<<nb, 256, 0, stream>>>(ebuf, boff, x, csr, off_g, dinv, xd, n, nb);

    k_agg1   <<<(n + 7) / 8, 256, 0, stream>>>(xd, csr, off_g, dinv, b1, W1, W2, g2, n);
    k_agg2   <<<(n + 7) / 8, 256, 0, stream>>>(g2, csr, off_g, dinv, b2, out_h, out_ls, n);
}

// Round 11
// 109.479 us; speedup vs baseline: 9.2075x; 1.0924x over previous
//
#include <hip/hip_runtime.h>
#include <hip/hip_bf16.h>
#include <hip/hip_fp16.h>
#include <math.h>
#include <stdint.h>

#define F_IN  32
#define F_HID 32
#define F_OUT 16
#define NPB     256    // nodes per bucket
#define LOG_NPB 8
#define MAXNB   512    // supports n <= 131072
#define BH      256    // histogram/fill blocks

__device__ inline uint32_t pk_add(uint32_t a, uint32_t b) {
    union { uint32_t u; __half2 h; } x, y, r;
    x.u = a; y.u = b;
    r.h = __hadd2(x.h, y.h);
    return r.u;
}
__device__ inline uint4 pk_add4(uint4 a, uint4 b) {
    a.x = pk_add(a.x, b.x); a.y = pk_add(a.y, b.y);
    a.z = pk_add(a.z, b.z); a.w = pk_add(a.w, b.w);
    return a;
}
__device__ inline uint2 pk_add2(uint2 a, uint2 b) {
    a.x = pk_add(a.x, b.x); a.y = pk_add(a.y, b.y);
    return a;
}

__device__ inline float fexp(float x) {           // e^x
    return __builtin_amdgcn_exp2f(x * 1.44269504089f);
}
__device__ inline float ftanh(float x) {          // tanh via exp2+rcp
    x = fminf(fmaxf(x, -15.f), 15.f);
    float t = __builtin_amdgcn_exp2f(x * 2.88539008178f);  // e^(2x)
    return (t - 1.0f) * __builtin_amdgcn_rcpf(t + 1.0f);
}

// ---- pass A: per-block bucket histogram (vectorized dst reads) ----
__launch_bounds__(1024)
__global__ void k_hist(const int* __restrict__ ei, int ne, int chunk, int nb,
                       int* __restrict__ hist_mat) {
    __shared__ int hist[MAXNB];
    int t = threadIdx.x, b = blockIdx.x;
    for (int i = t; i < nb; i += 1024) hist[i] = 0;
    __syncthreads();
    long s = (long)b * chunk;
    long e = s + chunk; if (e > ne) e = ne;
    const int* dstp = ei + ne;
    long i = s + (long)t * 4;
    for (; i + 4 <= e; i += 4096) {
        int4 d = *(const int4*)(dstp + i);
        atomicAdd(&hist[d.x >> LOG_NPB], 1);
        atomicAdd(&hist[d.y >> LOG_NPB], 1);
        atomicAdd(&hist[d.z >> LOG_NPB], 1);
        atomicAdd(&hist[d.w >> LOG_NPB], 1);
    }
    if (i < e)
        for (long j = i; j < e; ++j) atomicAdd(&hist[dstp[j] >> LOG_NPB], 1);
    __syncthreads();
    for (int k = t; k < nb; k += 1024)
        hist_mat[(size_t)b * nb + k] = hist[k];
}

// ---- column scan: off_mat[b][k] = per-block exclusive prefix; totalG[k] = col sum ----
__global__ void k_colscan(const int* __restrict__ hist_mat, int* __restrict__ off_mat,
                          int* __restrict__ totalG, int nb) {
    int k = blockIdx.x * 256 + threadIdx.x;
    if (k >= nb) return;
    int run = 0;
    #pragma unroll 8
    for (int b = 0; b < BH; ++b) {
        size_t idx = (size_t)b * nb + k;
        int h = hist_mat[idx];
        off_mat[idx] = run;
        run += h;
    }
    totalG[k] = run;
}

// ---- exclusive scan of totalG -> boff[0..nb] (single block) ----
__global__ void k_scanb(const int* __restrict__ totalG, int* __restrict__ boff, int nb) {
    __shared__ int sh[256];
    int t = threadIdx.x;
    int base = t * 2;
    int v[2], s = 0;
    #pragma unroll
    for (int j = 0; j < 2; ++j) {
        v[j] = (base + j < nb) ? totalG[base + j] : 0;
        s += v[j];
    }
    sh[t] = s; __syncthreads();
    for (int o = 1; o < 256; o <<= 1) {
        int u = (t >= o) ? sh[t - o] : 0;
        __syncthreads();
        sh[t] += u;
        __syncthreads();
    }
    int run = sh[t] - s;  // exclusive prefix
    #pragma unroll
    for (int j = 0; j < 2; ++j) {
        int k = base + j;
        if (k < nb) { boff[k] = run; run += v[j]; }
    }
    if (t == 255) boff[nb] = sh[255];
}

// ---- pass C: place edges into bucket-grouped ebuf via LDS cursors ----
__launch_bounds__(1024)
__global__ void k_fillc(const int* __restrict__ ei, int ne, int chunk, int nb,
                        const int* __restrict__ off_mat, const int* __restrict__ boff,
                        uint32_t* __restrict__ ebuf) {
    __shared__ int cur[MAXNB];
    int t = threadIdx.x, b = blockIdx.x;
    for (int i = t; i < nb; i += 1024)
        cur[i] = off_mat[(size_t)b * nb + i] + boff[i];
    __syncthreads();
    long s = (long)b * chunk;
    long e = s + chunk; if (e > ne) e = ne;
    const int* srcp = ei;
    const int* dstp = ei + ne;
    long i = s + (long)t * 4;
    for (; i + 4 <= e; i += 4096) {
        int4 sv = *(const int4*)(srcp + i);
        int4 dv = *(const int4*)(dstp + i);
        int p0 = atomicAdd(&cur[dv.x >> LOG_NPB], 1);
        ebuf[p0] = (uint32_t)sv.x | ((uint32_t)(dv.x & (NPB - 1)) << 17);
        int p1 = atomicAdd(&cur[dv.y >> LOG_NPB], 1);
        ebuf[p1] = (uint32_t)sv.y | ((uint32_t)(dv.y & (NPB - 1)) << 17);
        int p2 = atomicAdd(&cur[dv.z >> LOG_NPB], 1);
        ebuf[p2] = (uint32_t)sv.z | ((uint32_t)(dv.z & (NPB - 1)) << 17);
        int p3 = atomicAdd(&cur[dv.w >> LOG_NPB], 1);
        ebuf[p3] = (uint32_t)sv.w | ((uint32_t)(dv.w & (NPB - 1)) << 17);
    }
    if (i < e) {
        for (long j = i; j < e; ++j) {
            int sn = srcp[j], dn = dstp[j];
            int p = atomicAdd(&cur[dn >> LOG_NPB], 1);
            ebuf[p] = (uint32_t)sn | ((uint32_t)(dn & (NPB - 1)) << 17);
        }
    }
}

// ---- pass 2: within-bucket sort -> csr + off_g + dinv + xd = x*dinv (f16x2) ----
__launch_bounds__(256)
__global__ void k_pass2(const uint32_t* __restrict__ ebuf, const int* __restrict__ boff,
                        const float* __restrict__ x,
                        int* __restrict__ csr, int* __restrict__ off_g,
                        float* __restrict__ dinv, uint32_t* __restrict__ xd,
                        int n, int nb) {
    __shared__ int hist[NPB], scn[NPB], cur[NPB];
    __shared__ float sdi[NPB];
    int b = blockIdx.x, t = threadIdx.x;
    int base = boff[b], end = boff[b + 1];
    int v0 = b << LOG_NPB;
    hist[t] = 0;
    __syncthreads();
    for (int i = base + t; i < end; i += 256)
        atomicAdd(&hist[(ebuf[i] >> 17) & (NPB - 1)], 1);
    __syncthreads();
    int val = hist[t];
    scn[t] = val; __syncthreads();
    for (int o = 1; o < 256; o <<= 1) {
        int u = (t >= o) ? scn[t - o] : 0;
        __syncthreads();
        scn[t] += u;
        __syncthreads();
    }
    int excl = scn[t] - val + base;
    cur[t] = excl;
    int v = v0 + t;
    float d = 0.f;
    if (v < n) {
        off_g[v] = excl;
        d = rsqrtf((float)(val + 1));  // +1 self-loop
        dinv[v] = d;
    }
    sdi[t] = d;
    if (b == nb - 1 && t == 0) off_g[n] = end;
    if (b == nb - 1 && t < 16) xd[(size_t)n * 16 + t] = 0u;  // zero row for padding
    __syncthreads();
    for (int i = base + t; i < end; i += 256) {
        uint32_t r = ebuf[i];
        int slot = atomicAdd(&cur[(r >> 17) & (NPB - 1)], 1);
        csr[slot] = (int)(r & 0x1FFFF);
    }
    // xd = x * dinv, packed f16x2 (16 words/node)
    for (int i = t; i < NPB * 16; i += 256) {
        int nl = i >> 4, wp = i & 15;
        int vv = v0 + nl;
        if (vv < n) {
            float2 xx = *(const float2*)(x + (size_t)vv * F_IN + 2 * wp);
            float di = sdi[nl];
            union { __half2 h; uint32_t u; } pk;
            pk.h = __floats2half2_rn(xx.x * di, xx.y * di);
            xd[(size_t)vv * 16 + wp] = pk.u;
        }
    }
}

// ---- agg1: gather xd (4-deep batched), then (sum@W1 -> tanh -> @W2)*dinv -> g2 ----
__launch_bounds__(256)
__global__ void k_agg1(const uint32_t* __restrict__ xd, const int* __restrict__ csr,
                       const int* __restrict__ off_g,
                       const float* __restrict__ dinv, const float* __restrict__ b1,
                       const float* __restrict__ W1, const float* __restrict__ W2,
                       uint32_t* __restrict__ g2, int n) {
    __shared__ float W1s[F_IN * F_HID];
    __shared__ float W2s[F_HID * F_OUT];
    __shared__ float sums[8][F_IN + 1];
    __shared__ float hb[8][F_HID + 1];
    int t = threadIdx.x, wv = t >> 6, lane = t & 63;
    ((float4*)W1s)[t] = ((const float4*)W1)[t];               // 1024 floats
    if (t < 128) ((float4*)W2s)[t] = ((const float4*)W2)[t];  // 512 floats
    if (blockIdx.x == 0 && t < 8) g2[(size_t)n * 8 + t] = 0u; // zero row for agg2
    int half = lane >> 5, l = lane & 31;
    int v = blockIdx.x * 8 + wv * 2 + half;
    bool act = v < n;
    int q = l & 3, slot = l >> 2;  // 8 edge slots x 4 lanes x 16B per 64B row
    uint4 acc = make_uint4(0u, 0u, 0u, 0u);
    if (act) {
        if (slot == 0) acc = *(const uint4*)(xd + (size_t)v * 16 + q * 4);  // self
        int start = off_g[v], cnt = off_g[v + 1] - start;
        const int* cp = csr + start;
        // batched 4-deep gather (covers deg <= 32); invalid slots hit zero row n
        int i0 = (slot      < cnt) ? cp[slot]      : n;
        int i1 = (slot + 8  < cnt) ? cp[slot + 8]  : n;
        int i2 = (slot + 16 < cnt) ? cp[slot + 16] : n;
        int i3 = (slot + 24 < cnt) ? cp[slot + 24] : n;
        uint4 w0 = *(const uint4*)(xd + (size_t)i0 * 16 + q * 4);
        uint4 w1 = *(const uint4*)(xd + (size_t)i1 * 16 + q * 4);
        uint4 w2 = *(const uint4*)(xd + (size_t)i2 * 16 + q * 4);
        uint4 w3 = *(const uint4*)(xd + (size_t)i3 * 16 + q * 4);
        acc = pk_add4(acc, w0);
        acc = pk_add4(acc, w1);
        acc = pk_add4(acc, w2);
        acc = pk_add4(acc, w3);
        for (int k = slot + 32; k < cnt; k += 8) {  // rare deg > 32
            int s = cp[k];
            acc = pk_add4(acc, *(const uint4*)(xd + (size_t)s * 16 + q * 4));
        }
    }
    #pragma unroll
    for (int off = 4; off < 32; off <<= 1) {   // butterfly across slots
        acc.x = pk_add(acc.x, (uint32_t)__shfl_xor((int)acc.x, off));
        acc.y = pk_add(acc.y, (uint32_t)__shfl_xor((int)acc.y, off));
        acc.z = pk_add(acc.z, (uint32_t)__shfl_xor((int)acc.z, off));
        acc.w = pk_add(acc.w, (uint32_t)__shfl_xor((int)acc.w, off));
    }
    // redistribute: lane l takes channel ch=l of its half's node
    int ch = l;
    int src = (lane & 32) + (ch >> 3);  // lane with q == ch>>3
    uint32_t a0 = (uint32_t)__shfl((int)acc.x, src);
    uint32_t a1 = (uint32_t)__shfl((int)acc.y, src);
    uint32_t a2 = (uint32_t)__shfl((int)acc.z, src);
    uint32_t a3 = (uint32_t)__shfl((int)acc.w, src);
    int widx = (ch & 7) >> 1;
    uint32_t w = (widx & 2) ? ((widx & 1) ? a3 : a2) : ((widx & 1) ? a1 : a0);
    union { uint32_t u; __half2 h; } pw; pw.u = w;
    float2 f2 = __half22float2(pw.h);
    sums[wv * 2 + half][ch] = (ch & 1) ? f2.y : f2.x;
    __syncthreads();
    // matmul1 + tanh: 256 threads = 8 nodes x 32 ch
    {
        int nl = t >> 5, c = t & 31;
        int v1 = blockIdx.x * 8 + nl;
        float di = (v1 < n) ? dinv[v1] : 0.f;
        float s = 0.f;
        #pragma unroll
        for (int k = 0; k < F_IN; ++k) s += sums[nl][k] * W1s[k * F_HID + c];
        hb[nl][c] = ftanh(s * di + b1[c]);
    }
    __syncthreads();
    // matmul2: g2 = (h @ W2) * dinv, packed f16x2 (8 words/node)
    if (t < 128) {
        int nl = t >> 4, c = t & 15;
        int v2 = blockIdx.x * 8 + nl;
        float s = 0.f;
        #pragma unroll
        for (int k = 0; k < F_HID; ++k) s += hb[nl][k] * W2s[k * F_OUT + c];
        float gv = (v2 < n) ? s * dinv[v2] : 0.f;
        float hi2 = __shfl_xor(gv, 1);
        if ((c & 1) == 0 && v2 < n) {
            union { __half2 h; uint32_t u; } pk2;
            pk2.h = __floats2half2_rn(gv, hi2);
            g2[(size_t)v2 * 8 + (c >> 1)] = pk2.u;
        }
    }
}

// ---- agg2: 4-deep batched gather; all-lane epilogue + fused log_softmax ----
__launch_bounds__(256)
__global__ void k_agg2(const uint32_t* __restrict__ g2, const int* __restrict__ csr,
                       const int* __restrict__ off_g,
                       const float* __restrict__ dinv, const float* __restrict__ b2,
                       float* __restrict__ out_h, float* __restrict__ out_ls, int n) {
    int t = threadIdx.x, wv = t >> 6, lane = t & 63;
    int half = lane >> 5, l = lane & 31;
    int v = blockIdx.x * 8 + wv * 2 + half;
    bool act = v < n;
    int q = l & 3, slot = l >> 2;  // 8 slots x 4 lanes x 8B per 32B row
    uint2 acc = make_uint2(0u, 0u);
    if (act) {
        if (slot == 0) acc = *(const uint2*)(g2 + (size_t)v * 8 + q * 2);  // self
        int start = off_g[v], cnt = off_g[v + 1] - start;
        const int* cp = csr + start;
        int i0 = (slot      < cnt) ? cp[slot]      : n;
        int i1 = (slot + 8  < cnt) ? cp[slot + 8]  : n;
        int i2 = (slot + 16 < cnt) ? cp[slot + 16] : n;
        int i3 = (slot + 24 < cnt) ? cp[slot + 24] : n;
        uint2 w0 = *(const uint2*)(g2 + (size_t)i0 * 8 + q * 2);
        uint2 w1 = *(const uint2*)(g2 + (size_t)i1 * 8 + q * 2);
        uint2 w2 = *(const uint2*)(g2 + (size_t)i2 * 8 + q * 2);
        uint2 w3 = *(const uint2*)(g2 + (size_t)i3 * 8 + q * 2);
        acc = pk_add2(acc, w0);
        acc = pk_add2(acc, w1);
        acc = pk_add2(acc, w2);
        acc = pk_add2(acc, w3);
        for (int k = slot + 32; k < cnt; k += 8) {
            int s = cp[k];
            acc = pk_add2(acc, *(const uint2*)(g2 + (size_t)s * 8 + q * 2));
        }
    }
    #pragma unroll
    for (int off = 4; off < 32; off <<= 1) {
        acc.x = pk_add(acc.x, (uint32_t)__shfl_xor((int)acc.x, off));
        acc.y = pk_add(acc.y, (uint32_t)__shfl_xor((int)acc.y, off));
    }
    if (l < 16) {
        int ch = l;
        int src = (lane & 32) + (ch >> 2);  // lane with q == ch>>2
        uint32_t a0 = (uint32_t)__shfl((int)acc.x, src);
        uint32_t a1 = (uint32_t)__shfl((int)acc.y, src);
        uint32_t w = (ch & 2) ? a1 : a0;
        union { uint32_t u; __half2 h; } pw; pw.u = w;
        float2 f2 = __half22float2(pw.h);
        float f = (ch & 1) ? f2.y : f2.x;
        float di = act ? dinv[v] : 0.f;
        float val = f * di + b2[ch];
        float m = val;
        m = fmaxf(m, __shfl_xor(m, 1));
        m = fmaxf(m, __shfl_xor(m, 2));
        m = fmaxf(m, __shfl_xor(m, 4));
        m = fmaxf(m, __shfl_xor(m, 8));
        float S = fexp(val - m);
        S += __shfl_xor(S, 1);
        S += __shfl_xor(S, 2);
        S += __shfl_xor(S, 4);
        S += __shfl_xor(S, 8);
        float L = __builtin_amdgcn_logf(S) * 0.69314718056f + m;
        if (act) {
            out_h[(size_t)v * F_OUT + ch]  = val;
            out_ls[(size_t)v * F_OUT + ch] = val - L;
        }
    }
}

static inline size_t align16(size_t x) { return (x + 15) & ~(size_t)15; }

extern "C" void kernel_launch(void* const* d_in, const int* in_sizes, int n_in,
                              void* d_out, int out_size, void* d_ws, size_t ws_size,
                              hipStream_t stream) {
    const float* x  = (const float*)d_in[0];
    const int*   ei = (const int*)d_in[1];   // [2,E]: [0:E]=src, [E:2E]=dst
    const float* W1 = (const float*)d_in[2];
    const float* b1 = (const float*)d_in[3];
    const float* W2 = (const float*)d_in[4];
    const float* b2 = (const float*)d_in[5];

    int n  = in_sizes[0] / F_IN;
    int ne = in_sizes[1] / 2;
    int nb = (n + NPB - 1) / NPB;
    int chunk = (((ne + BH - 1) / BH) + 3) & ~3;  // multiple of 4 for int4 loads

    float* out_h  = (float*)d_out;
    float* out_ls = out_h + (size_t)n * F_OUT;

    char* p = (char*)d_ws;
    float*    dinv     = (float*)p;    p += align16((size_t)n * sizeof(float));
    int*      totalG   = (int*)p;      p += align16(MAXNB * sizeof(int));
    int*      boff     = (int*)p;      p += align16((MAXNB + 4) * sizeof(int));
    int*      off_g    = (int*)p;      p += align16(((size_t)n + 4) * sizeof(int));
    int*      hist_mat = (int*)p;      p += align16((size_t)BH * nb * sizeof(int));
    int*      off_mat  = (int*)p;      p += align16((size_t)BH * nb * sizeof(int));
    uint32_t* ebuf     = (uint32_t*)p; p += align16((size_t)ne * sizeof(uint32_t));
    int*      csr      = (int*)p;      p += align16((size_t)ne * sizeof(int));
    uint32_t* xd       = (uint32_t*)p; p += align16(((size_t)n + 1) * 16 * sizeof(uint32_t));
    uint32_t* g2       = (uint32_t*)p; p += align16(((size_t)n + 1) * 8 * sizeof(uint32_t));

    k_hist   <<<BH, 1024, 0, stream>>>(ei, ne, chunk, nb, hist_mat);
    k_colscan<<<(nb + 255) / 256, 256, 0, stream>>>(hist_mat, off_mat, totalG, nb);
    k_scanb  <<<1, 256, 0, stream>>>(totalG, boff, nb);
    k_fillc  <<<BH, 1024, 0, stream>>>(ei, ne, chunk, nb, off_mat, boff, ebuf);
    k_pass2  <<<nb, 256, 0, stream>>>(ebuf, boff, x, csr, off_g, dinv, xd, n, nb);

    k_agg1   <<<(n + 7) / 8, 256, 0, stream>>>(xd, csr, off_g, dinv, b1, W1, W2, g2, n);
    k_agg2   <<<(n + 7) / 8, 256, 0, stream>>>(g2, csr, off_g, dinv, b2, out_h, out_ls, n);
}

// Round 12
// 101.480 us; speedup vs baseline: 9.9334x; 1.0788x over previous
//
#include <hip/hip_runtime.h>
#include <hip/hip_bf16.h>
#include <hip/hip_fp16.h>
#include <math.h>
#include <stdint.h>

#define F_IN  32
#define F_HID 32
#define F_OUT 16
#define NPB     256    // nodes per bucket
#define LOG_NPB 8
#define MAXNB   512    // supports n <= 131072
#define BH      512    // histogram/fill blocks

__device__ inline uint32_t pk_add(uint32_t a, uint32_t b) {
    union { uint32_t u; __half2 h; } x, y, r;
    x.u = a; y.u = b;
    r.h = __hadd2(x.h, y.h);
    return r.u;
}
__device__ inline uint4 pk_add4(uint4 a, uint4 b) {
    a.x = pk_add(a.x, b.x); a.y = pk_add(a.y, b.y);
    a.z = pk_add(a.z, b.z); a.w = pk_add(a.w, b.w);
    return a;
}
__device__ inline uint2 pk_add2(uint2 a, uint2 b) {
    a.x = pk_add(a.x, b.x); a.y = pk_add(a.y, b.y);
    return a;
}

__device__ inline float fexp(float x) {           // e^x
    return __builtin_amdgcn_exp2f(x * 1.44269504089f);
}
__device__ inline float ftanh(float x) {          // tanh via exp2+rcp
    x = fminf(fmaxf(x, -15.f), 15.f);
    float t = __builtin_amdgcn_exp2f(x * 2.88539008178f);  // e^(2x)
    return (t - 1.0f) * __builtin_amdgcn_rcpf(t + 1.0f);
}

// ---- pass A: per-block bucket histogram, 4 replicated sub-hists ----
__launch_bounds__(512)
__global__ void k_hist(const int* __restrict__ ei, int ne, int chunk, int nb,
                       int* __restrict__ hist_mat) {
    __shared__ int hist[4][MAXNB];
    int t = threadIdx.x, b = blockIdx.x;
    int rep = t >> 7;  // 128-thread groups
    for (int i = t; i < 4 * MAXNB; i += 512) ((int*)hist)[i] = 0;
    __syncthreads();
    long s = (long)b * chunk;
    long e = s + chunk; if (e > ne) e = ne;
    const int* dstp = ei + ne;
    long i = s + (long)t * 4;
    for (; i + 4 <= e; i += 2048) {
        int4 d = *(const int4*)(dstp + i);
        atomicAdd(&hist[rep][d.x >> LOG_NPB], 1);
        atomicAdd(&hist[rep][d.y >> LOG_NPB], 1);
        atomicAdd(&hist[rep][d.z >> LOG_NPB], 1);
        atomicAdd(&hist[rep][d.w >> LOG_NPB], 1);
    }
    if (i < e)
        for (long j = i; j < e; ++j) atomicAdd(&hist[rep][dstp[j] >> LOG_NPB], 1);
    __syncthreads();
    for (int k = t; k < nb; k += 512)
        hist_mat[(size_t)b * nb + k] = hist[0][k] + hist[1][k] + hist[2][k] + hist[3][k];
}

// ---- column scan (wave per column): off_mat[b][k] = col-exclusive prefix ----
__launch_bounds__(64)
__global__ void k_colscan(const int* __restrict__ hist_mat, int* __restrict__ off_mat,
                          int* __restrict__ totalG, int nb) {
    int k = blockIdx.x;
    if (k >= nb) return;
    int lane = threadIdx.x;
    int run = 0;
    #pragma unroll
    for (int c = 0; c < BH; c += 64) {
        size_t idx = (size_t)(c + lane) * nb + k;
        int v = hist_mat[idx];
        int inc = v;
        #pragma unroll
        for (int o = 1; o < 64; o <<= 1) {
            int u = __shfl_up(inc, o);
            if (lane >= o) inc += u;
        }
        off_mat[idx] = run + inc - v;
        run += __shfl(inc, 63);
    }
    if (lane == 0) totalG[k] = run;
}

// ---- exclusive scan of totalG -> boff[0..nb] (single block) ----
__global__ void k_scanb(const int* __restrict__ totalG, int* __restrict__ boff, int nb) {
    __shared__ int sh[256];
    int t = threadIdx.x;
    int base = t * 2;
    int v[2], s = 0;
    #pragma unroll
    for (int j = 0; j < 2; ++j) {
        v[j] = (base + j < nb) ? totalG[base + j] : 0;
        s += v[j];
    }
    sh[t] = s; __syncthreads();
    for (int o = 1; o < 256; o <<= 1) {
        int u = (t >= o) ? sh[t - o] : 0;
        __syncthreads();
        sh[t] += u;
        __syncthreads();
    }
    int run = sh[t] - s;  // exclusive prefix
    #pragma unroll
    for (int j = 0; j < 2; ++j) {
        int k = base + j;
        if (k < nb) { boff[k] = run; run += v[j]; }
    }
    if (t == 255) boff[nb] = sh[255];
}

// ---- pass C: place edges into bucket-grouped ebuf via LDS cursors ----
__launch_bounds__(512)
__global__ void k_fillc(const int* __restrict__ ei, int ne, int chunk, int nb,
                        const int* __restrict__ off_mat, const int* __restrict__ boff,
                        uint32_t* __restrict__ ebuf) {
    __shared__ int cur[MAXNB];
    int t = threadIdx.x, b = blockIdx.x;
    for (int i = t; i < nb; i += 512)
        cur[i] = off_mat[(size_t)b * nb + i] + boff[i];
    __syncthreads();
    long s = (long)b * chunk;
    long e = s + chunk; if (e > ne) e = ne;
    const int* srcp = ei;
    const int* dstp = ei + ne;
    long i = s + (long)t * 4;
    for (; i + 4 <= e; i += 2048) {
        int4 sv = *(const int4*)(srcp + i);
        int4 dv = *(const int4*)(dstp + i);
        int p0 = atomicAdd(&cur[dv.x >> LOG_NPB], 1);
        ebuf[p0] = (uint32_t)sv.x | ((uint32_t)(dv.x & (NPB - 1)) << 17);
        int p1 = atomicAdd(&cur[dv.y >> LOG_NPB], 1);
        ebuf[p1] = (uint32_t)sv.y | ((uint32_t)(dv.y & (NPB - 1)) << 17);
        int p2 = atomicAdd(&cur[dv.z >> LOG_NPB], 1);
        ebuf[p2] = (uint32_t)sv.z | ((uint32_t)(dv.z & (NPB - 1)) << 17);
        int p3 = atomicAdd(&cur[dv.w >> LOG_NPB], 1);
        ebuf[p3] = (uint32_t)sv.w | ((uint32_t)(dv.w & (NPB - 1)) << 17);
    }
    if (i < e) {
        for (long j = i; j < e; ++j) {
            int sn = srcp[j], dn = dstp[j];
            int p = atomicAdd(&cur[dn >> LOG_NPB], 1);
            ebuf[p] = (uint32_t)sn | ((uint32_t)(dn & (NPB - 1)) << 17);
        }
    }
}

// ---- pass 2: within-bucket sort -> csr + off_g + dinv + xd = x*dinv (f16x2) ----
__launch_bounds__(256)
__global__ void k_pass2(const uint32_t* __restrict__ ebuf, const int* __restrict__ boff,
                        const float* __restrict__ x,
                        int* __restrict__ csr, int* __restrict__ off_g,
                        float* __restrict__ dinv, uint32_t* __restrict__ xd,
                        int n, int nb) {
    __shared__ int hist[NPB], scn[NPB], cur[NPB];
    __shared__ float sdi[NPB];
    int b = blockIdx.x, t = threadIdx.x;
    int base = boff[b], end = boff[b + 1];
    int v0 = b << LOG_NPB;
    hist[t] = 0;
    __syncthreads();
    for (int i = base + t; i < end; i += 256)
        atomicAdd(&hist[(ebuf[i] >> 17) & (NPB - 1)], 1);
    __syncthreads();
    int val = hist[t];
    scn[t] = val; __syncthreads();
    for (int o = 1; o < 256; o <<= 1) {
        int u = (t >= o) ? scn[t - o] : 0;
        __syncthreads();
        scn[t] += u;
        __syncthreads();
    }
    int excl = scn[t] - val + base;
    cur[t] = excl;
    int v = v0 + t;
    float d = 0.f;
    if (v < n) {
        off_g[v] = excl;
        d = rsqrtf((float)(val + 1));  // +1 self-loop
        dinv[v] = d;
    }
    sdi[t] = d;
    if (b == nb - 1 && t == 0) off_g[n] = end;
    if (b == nb - 1 && t < 16) xd[(size_t)n * 16 + t] = 0u;  // zero row for padding
    __syncthreads();
    for (int i = base + t; i < end; i += 256) {
        uint32_t r = ebuf[i];
        int slot = atomicAdd(&cur[(r >> 17) & (NPB - 1)], 1);
        csr[slot] = (int)(r & 0x1FFFF);
    }
    // xd = x * dinv, packed f16x2 (16 words/node)
    for (int i = t; i < NPB * 16; i += 256) {
        int nl = i >> 4, wp = i & 15;
        int vv = v0 + nl;
        if (vv < n) {
            float2 xx = *(const float2*)(x + (size_t)vv * F_IN + 2 * wp);
            float di = sdi[nl];
            union { __half2 h; uint32_t u; } pk;
            pk.h = __floats2half2_rn(xx.x * di, xx.y * di);
            xd[(size_t)vv * 16 + wp] = pk.u;
        }
    }
}

// ---- agg1: gather xd (4-deep batched), then (sum@W1 -> tanh -> @W2)*dinv -> g2 ----
__launch_bounds__(256)
__global__ void k_agg1(const uint32_t* __restrict__ xd, const int* __restrict__ csr,
                       const int* __restrict__ off_g,
                       const float* __restrict__ dinv, const float* __restrict__ b1,
                       const float* __restrict__ W1, const float* __restrict__ W2,
                       uint32_t* __restrict__ g2, int n) {
    __shared__ float W1s[F_IN * F_HID];
    __shared__ float W2s[F_HID * F_OUT];
    __shared__ float sums[8][F_IN + 1];
    __shared__ float hb[8][F_HID + 1];
    int t = threadIdx.x, wv = t >> 6, lane = t & 63;
    ((float4*)W1s)[t] = ((const float4*)W1)[t];               // 1024 floats
    if (t < 128) ((float4*)W2s)[t] = ((const float4*)W2)[t];  // 512 floats
    if (blockIdx.x == 0 && t < 8) g2[(size_t)n * 8 + t] = 0u; // zero row for agg2
    int half = lane >> 5, l = lane & 31;
    int v = blockIdx.x * 8 + wv * 2 + half;
    bool act = v < n;
    int q = l & 3, slot = l >> 2;  // 8 edge slots x 4 lanes x 16B per 64B row
    uint4 acc = make_uint4(0u, 0u, 0u, 0u);
    if (act) {
        if (slot == 0) acc = *(const uint4*)(xd + (size_t)v * 16 + q * 4);  // self
        int start = off_g[v], cnt = off_g[v + 1] - start;
        const int* cp = csr + start;
        // batched 4-deep gather (covers deg <= 32); invalid slots hit zero row n
        int i0 = (slot      < cnt) ? cp[slot]      : n;
        int i1 = (slot + 8  < cnt) ? cp[slot + 8]  : n;
        int i2 = (slot + 16 < cnt) ? cp[slot + 16] : n;
        int i3 = (slot + 24 < cnt) ? cp[slot + 24] : n;
        uint4 w0 = *(const uint4*)(xd + (size_t)i0 * 16 + q * 4);
        uint4 w1 = *(const uint4*)(xd + (size_t)i1 * 16 + q * 4);
        uint4 w2 = *(const uint4*)(xd + (size_t)i2 * 16 + q * 4);
        uint4 w3 = *(const uint4*)(xd + (size_t)i3 * 16 + q * 4);
        acc = pk_add4(acc, w0);
        acc = pk_add4(acc, w1);
        acc = pk_add4(acc, w2);
        acc = pk_add4(acc, w3);
        for (int k = slot + 32; k < cnt; k += 8) {  // rare deg > 32
            int s = cp[k];
            acc = pk_add4(acc, *(const uint4*)(xd + (size_t)s * 16 + q * 4));
        }
    }
    #pragma unroll
    for (int off = 4; off < 32; off <<= 1) {   // butterfly across slots
        acc.x = pk_add(acc.x, (uint32_t)__shfl_xor((int)acc.x, off));
        acc.y = pk_add(acc.y, (uint32_t)__shfl_xor((int)acc.y, off));
        acc.z = pk_add(acc.z, (uint32_t)__shfl_xor((int)acc.z, off));
        acc.w = pk_add(acc.w, (uint32_t)__shfl_xor((int)acc.w, off));
    }
    // redistribute: lane l takes channel ch=l of its half's node
    int ch = l;
    int src = (lane & 32) + (ch >> 3);  // lane with q == ch>>3
    uint32_t a0 = (uint32_t)__shfl((int)acc.x, src);
    uint32_t a1 = (uint32_t)__shfl((int)acc.y, src);
    uint32_t a2 = (uint32_t)__shfl((int)acc.z, src);
    uint32_t a3 = (uint32_t)__shfl((int)acc.w, src);
    int widx = (ch & 7) >> 1;
    uint32_t w = (widx & 2) ? ((widx & 1) ? a3 : a2) : ((widx & 1) ? a1 : a0);
    union { uint32_t u; __half2 h; } pw; pw.u = w;
    float2 f2 = __half22float2(pw.h);
    sums[wv * 2 + half][ch] = (ch & 1) ? f2.y : f2.x;
    __syncthreads();
    // matmul1 + tanh: 256 threads = 8 nodes x 32 ch
    {
        int nl = t >> 5, c = t & 31;
        int v1 = blockIdx.x * 8 + nl;
        float di = (v1 < n) ? dinv[v1] : 0.f;
        float s = 0.f;
        #pragma unroll
        for (int k = 0; k < F_IN; ++k) s += sums[nl][k] * W1s[k * F_HID + c];
        hb[nl][c] = ftanh(s * di + b1[c]);
    }
    __syncthreads();
    // matmul2: g2 = (h @ W2) * dinv, packed f16x2 (8 words/node)
    if (t < 128) {
        int nl = t >> 4, c = t & 15;
        int v2 = blockIdx.x * 8 + nl;
        float s = 0.f;
        #pragma unroll
        for (int k = 0; k < F_HID; ++k) s += hb[nl][k] * W2s[k * F_OUT + c];
        float gv = (v2 < n) ? s * dinv[v2] : 0.f;
        float hi2 = __shfl_xor(gv, 1);
        if ((c & 1) == 0 && v2 < n) {
            union { __half2 h; uint32_t u; } pk2;
            pk2.h = __floats2half2_rn(gv, hi2);
            g2[(size_t)v2 * 8 + (c >> 1)] = pk2.u;
        }
    }
}

// ---- agg2: 4-deep batched gather; all-lane epilogue + fused log_softmax ----
__launch_bounds__(256)
__global__ void k_agg2(const uint32_t* __restrict__ g2, const int* __restrict__ csr,
                       const int* __restrict__ off_g,
                       const float* __restrict__ dinv, const float* __restrict__ b2,
                       float* __restrict__ out_h, float* __restrict__ out_ls, int n) {
    int t = threadIdx.x, wv = t >> 6, lane = t & 63;
    int half = lane >> 5, l = lane & 31;
    int v = blockIdx.x * 8 + wv * 2 + half;
    bool act = v < n;
    int q = l & 3, slot = l >> 2;  // 8 slots x 4 lanes x 8B per 32B row
    uint2 acc = make_uint2(0u, 0u);
    if (act) {
        if (slot == 0) acc = *(const uint2*)(g2 + (size_t)v * 8 + q * 2);  // self
        int start = off_g[v], cnt = off_g[v + 1] - start;
        const int* cp = csr + start;
        int i0 = (slot      < cnt) ? cp[slot]      : n;
        int i1 = (slot + 8  < cnt) ? cp[slot + 8]  : n;
        int i2 = (slot + 16 < cnt) ? cp[slot + 16] : n;
        int i3 = (slot + 24 < cnt) ? cp[slot + 24] : n;
        uint2 w0 = *(const uint2*)(g2 + (size_t)i0 * 8 + q * 2);
        uint2 w1 = *(const uint2*)(g2 + (size_t)i1 * 8 + q * 2);
        uint2 w2 = *(const uint2*)(g2 + (size_t)i2 * 8 + q * 2);
        uint2 w3 = *(const uint2*)(g2 + (size_t)i3 * 8 + q * 2);
        acc = pk_add2(acc, w0);
        acc = pk_add2(acc, w1);
        acc = pk_add2(acc, w2);
        acc = pk_add2(acc, w3);
        for (int k = slot + 32; k < cnt; k += 8) {
            int s = cp[k];
            acc = pk_add2(acc, *(const uint2*)(g2 + (size_t)s * 8 + q * 2));
        }
    }
    #pragma unroll
    for (int off = 4; off < 32; off <<= 1) {
        acc.x = pk_add(acc.x, (uint32_t)__shfl_xor((int)acc.x, off));
        acc.y = pk_add(acc.y, (uint32_t)__shfl_xor((int)acc.y, off));
    }
    if (l < 16) {
        int ch = l;
        int src = (lane & 32) + (ch >> 2);  // lane with q == ch>>2
        uint32_t a0 = (uint32_t)__shfl((int)acc.x, src);
        uint32_t a1 = (uint32_t)__shfl((int)acc.y, src);
        uint32_t w = (ch & 2) ? a1 : a0;
        union { uint32_t u; __half2 h; } pw; pw.u = w;
        float2 f2 = __half22float2(pw.h);
        float f = (ch & 1) ? f2.y : f2.x;
        float di = act ? dinv[v] : 0.f;
        float val = f * di + b2[ch];
        float m = val;
        m = fmaxf(m, __shfl_xor(m, 1));
        m = fmaxf(m, __shfl_xor(m, 2));
        m = fmaxf(m, __shfl_xor(m, 4));
        m = fmaxf(m, __shfl_xor(m, 8));
        float S = fexp(val - m);
        S += __shfl_xor(S, 1);
        S += __shfl_xor(S, 2);
        S += __shfl_xor(S, 4);
        S += __shfl_xor(S, 8);
        float L = __builtin_amdgcn_logf(S) * 0.69314718056f + m;
        if (act) {
            out_h[(size_t)v * F_OUT + ch]  = val;
            out_ls[(size_t)v * F_OUT + ch] = val - L;
        }
    }
}

static inline size_t align16(size_t x) { return (x + 15) & ~(size_t)15; }

extern "C" void kernel_launch(void* const* d_in, const int* in_sizes, int n_in,
                              void* d_out, int out_size, void* d_ws, size_t ws_size,
                              hipStream_t stream) {
    const float* x  = (const float*)d_in[0];
    const int*   ei = (const int*)d_in[1];   // [2,E]: [0:E]=src, [E:2E]=dst
    const float* W1 = (const float*)d_in[2];
    const float* b1 = (const float*)d_in[3];
    const float* W2 = (const float*)d_in[4];
    const float* b2 = (const float*)d_in[5];

    int n  = in_sizes[0] / F_IN;
    int ne = in_sizes[1] / 2;
    int nb = (n + NPB - 1) / NPB;
    int chunk = (((ne + BH - 1) / BH) + 3) & ~3;  // multiple of 4 for int4 loads

    float* out_h  = (float*)d_out;
    float* out_ls = out_h + (size_t)n * F_OUT;

    char* p = (char*)d_ws;
    float*    dinv     = (float*)p;    p += align16((size_t)n * sizeof(float));
    int*      totalG   = (int*)p;      p += align16(MAXNB * sizeof(int));
    int*      boff     = (int*)p;      p += align16((MAXNB + 4) * sizeof(int));
    int*      off_g    = (int*)p;      p += align16(((size_t)n + 4) * sizeof(int));
    int*      hist_mat = (int*)p;      p += align16((size_t)BH * nb * sizeof(int));
    int*      off_mat  = (int*)p;      p += align16((size_t)BH * nb * sizeof(int));
    uint32_t* ebuf     = (uint32_t*)p; p += align16((size_t)ne * sizeof(uint32_t));
    int*      csr      = (int*)p;      p += align16((size_t)ne * sizeof(int));
    uint32_t* xd       = (uint32_t*)p; p += align16(((size_t)n + 1) * 16 * sizeof(uint32_t));
    uint32_t* g2       = (uint32_t*)p; p += align16(((size_t)n + 1) * 8 * sizeof(uint32_t));

    k_hist   <<<BH, 512, 0, stream>>>(ei, ne, chunk, nb, hist_mat);
    k_colscan<<<nb, 64, 0, stream>>>(hist_mat, off_mat, totalG, nb);
    k_scanb  <<<1, 256, 0, stream>>>(totalG, boff, nb);
    k_fillc  <<<BH, 512, 0, stream>>>(ei, ne, chunk, nb, off_mat, boff, ebuf);
    k_pass2  <<<nb, 256, 0, stream>>>(ebuf, boff, x, csr, off_g, dinv, xd, n, nb);

    k_agg1   <<<(n + 7) / 8, 256, 0, stream>>>(xd, csr, off_g, dinv, b1, W1, W2, g2, n);
    k_agg2   <<<(n + 7) / 8, 256, 0, stream>>>(g2, csr, off_g, dinv, b2, out_h, out_ls, n);
}